// Round 1
// baseline (1844.497 us; speedup 1.0000x reference)
//
#include <hip/hip_runtime.h>

#define NEG_SLOPE 0.2f
#define PRELU_W 0.1f

__device__ __forceinline__ float d_lrelu(float v){ return v >= 0.f ? v : NEG_SLOPE * v; }
__device__ __forceinline__ float d_prelu(float v){ return v >= 0.f ? v : PRELU_W * v; }

// ============================ CSR build ============================

__global__ void k_zero(int* __restrict__ p, int n){
  int i = blockIdx.x * 256 + threadIdx.x;
  if (i < n) p[i] = 0;
}

__global__ void k_count(const int* __restrict__ ei, int* __restrict__ deg, int E){
  int e = blockIdx.x * 256 + threadIdx.x;
  if (e < E) atomicAdd(&deg[ei[E + e]], 1);
}

// chunk=1024 per block (256 thr x 4)
__global__ void k_scan1(const int* __restrict__ deg, int* __restrict__ bsum, int n){
  int b = blockIdx.x, t = threadIdx.x;
  int base = b * 1024 + t * 4;
  int s = 0;
  #pragma unroll
  for (int k2 = 0; k2 < 4; ++k2){ int i = base + k2; if (i < n) s += deg[i]; }
  #pragma unroll
  for (int d = 32; d >= 1; d >>= 1) s += __shfl_xor(s, d, 64);
  __shared__ int ws[4];
  int lane = t & 63, wid = t >> 6;
  if (lane == 0) ws[wid] = s;
  __syncthreads();
  if (t == 0) bsum[b] = ws[0] + ws[1] + ws[2] + ws[3];
}

// single block, 128 threads: exclusive-scan bsum (nb <= 128), write rs[n]=total
__global__ void k_scan2(int* __restrict__ bsum, int nb, int* __restrict__ rs, int n){
  int t = threadIdx.x;
  int v = (t < nb) ? bsum[t] : 0;
  int x = v;
  int lane = t & 63, wid = t >> 6;
  #pragma unroll
  for (int d = 1; d < 64; d <<= 1){ int y = __shfl_up(x, d, 64); if (lane >= d) x += y; }
  __shared__ int wq[2];
  if (lane == 63) wq[wid] = x;
  __syncthreads();
  if (wid == 1) x += wq[0];
  if (t < nb) bsum[t] = x - v;
  if (t == nb - 1) rs[n] = x;
}

__global__ void k_scan3(const int* __restrict__ deg, const int* __restrict__ bsum,
                        int* __restrict__ rs, int n){
  int b = blockIdx.x, t = threadIdx.x;
  int base = b * 1024 + t * 4;
  int v[4];
  #pragma unroll
  for (int k2 = 0; k2 < 4; ++k2){ int i = base + k2; v[k2] = (i < n) ? deg[i] : 0; }
  int tsum = v[0] + v[1] + v[2] + v[3];
  int x = tsum;
  int lane = t & 63, wid = t >> 6;
  #pragma unroll
  for (int d = 1; d < 64; d <<= 1){ int y = __shfl_up(x, d, 64); if (lane >= d) x += y; }
  __shared__ int ws[4];
  if (lane == 63) ws[wid] = x;
  __syncthreads();
  int woff = 0;
  for (int w = 0; w < wid; ++w) woff += ws[w];
  int run = bsum[b] + woff + (x - tsum);
  #pragma unroll
  for (int k2 = 0; k2 < 4; ++k2){ int i = base + k2; if (i < n) rs[i] = run; run += v[k2]; }
}

__global__ void k_copy(const int* __restrict__ a, int* __restrict__ b, int n){
  int i = blockIdx.x * 256 + threadIdx.x;
  if (i < n) b[i] = a[i];
}

__global__ void k_scatter(const int* __restrict__ ei, int* __restrict__ cur,
                          int* __restrict__ col, int E){
  int e = blockIdx.x * 256 + threadIdx.x;
  if (e < E){
    int s = ei[e], d = ei[E + e];
    int p = atomicAdd(&cur[d], 1);
    col[p] = s;
  }
}

// ============================ GAT layer 1 (x is [N,1]) ============================
// h[s] = x[s]*W  => out[d] = (sum_j alpha_j x[s_j]) * W + b ; only scalar gathers.
__global__ void k_gat_l1(const int* __restrict__ rs, const int* __restrict__ col,
                         const float* __restrict__ x,
                         const float* __restrict__ W, const float* __restrict__ bias,
                         const float* __restrict__ a1v, const float* __restrict__ a2v,
                         float* __restrict__ outp, int n){
  int gid = blockIdx.x * 256 + threadIdx.x;
  int node = gid >> 5, k = gid & 31;
  if (node >= n) return;
  float Wk = W[k];
  float p1 = Wk * a1v[k], p2 = Wk * a2v[k];
  #pragma unroll
  for (int d = 16; d >= 1; d >>= 1){ p1 += __shfl_xor(p1, d, 32); p2 += __shfl_xor(p2, d, 32); }
  float a2d = x[node] * p2;
  int beg = rs[node], end = rs[node + 1];
  float denom = 0.f, accx = 0.f;
  for (int j = beg; j < end; ++j){
    int s = col[j];
    float xs = x[s];
    float e = d_lrelu(xs * p1 + a2d);
    float w = __expf(e);
    denom += w;
    accx += w * xs;
  }
  float o = accx / (denom + 1e-16f) * Wk + bias[k];
  outp[node * 32 + k] = d_prelu(o);
}

// ============================ per-layer linear ============================
// c = se+sk ; hS = c@WS ; hK = c@WK ; attention dots for both graphs.
__global__ void k_linear(const float* __restrict__ se, const float* __restrict__ sk,
                         const float* __restrict__ WS, const float* __restrict__ WK,
                         const float* __restrict__ a1S, const float* __restrict__ a2S,
                         const float* __restrict__ a1K, const float* __restrict__ a2K,
                         float* __restrict__ hS, float* __restrict__ hK,
                         float* __restrict__ oa1S, float* __restrict__ oa2S,
                         float* __restrict__ oa1K, float* __restrict__ oa2K, int n){
  __shared__ float sWS[1024], sWK[1024], sa[128];
  int t = threadIdx.x;
  for (int i = t; i < 1024; i += 256){ sWS[i] = WS[i]; sWK[i] = WK[i]; }
  if (t < 32){ sa[t] = a1S[t]; sa[32 + t] = a2S[t]; sa[64 + t] = a1K[t]; sa[96 + t] = a2K[t]; }
  __syncthreads();
  int gid = blockIdx.x * 256 + t;
  int node = gid >> 5, k = gid & 31;
  if (node >= n) return;
  float c = se[node * 32 + k] + sk[node * 32 + k];
  float hs = 0.f, hk = 0.f;
  #pragma unroll
  for (int m = 0; m < 32; ++m){
    float cm = __shfl(c, m, 32);
    hs += cm * sWS[m * 32 + k];
    hk += cm * sWK[m * 32 + k];
  }
  hS[node * 32 + k] = hs;
  hK[node * 32 + k] = hk;
  float r1 = hs * sa[k], r2 = hs * sa[32 + k], r3 = hk * sa[64 + k], r4 = hk * sa[96 + k];
  #pragma unroll
  for (int d = 16; d >= 1; d >>= 1){
    r1 += __shfl_xor(r1, d, 32); r2 += __shfl_xor(r2, d, 32);
    r3 += __shfl_xor(r3, d, 32); r4 += __shfl_xor(r4, d, 32);
  }
  if (k == 0){ oa1S[node] = r1; oa2S[node] = r2; oa1K[node] = r3; oa2K[node] = r4; }
}

// ============================ generic GAT aggregation ============================
// one 32-lane group per dst node; single pass (softmax shift-invariance).
__global__ void k_gat_agg(const int* __restrict__ rs, const int* __restrict__ col,
                          const float* __restrict__ h,
                          const float* __restrict__ a1, const float* __restrict__ a2,
                          const float* __restrict__ bias,
                          float* __restrict__ outp, int n){
  int gid = blockIdx.x * 256 + threadIdx.x;
  int node = gid >> 5, k = gid & 31;
  if (node >= n) return;
  float a2d = a2[node];
  int beg = rs[node], end = rs[node + 1];
  float denom = 0.f, acc = 0.f;
  for (int j = beg; j < end; ++j){
    int s = col[j];
    float e = d_lrelu(a1[s] + a2d);
    float w = __expf(e);
    denom += w;
    acc += w * h[s * 32 + k];
  }
  float o = acc / (denom + 1e-16f) + bias[k];
  outp[node * 32 + k] = d_prelu(o);
}

// ============================ output head 0 ============================
// comb = [se|sk]; final_dim0 = (relu(comb@Wos+bos)+relu(comb@Wok+bok))/2
__global__ void k_head0(const float* __restrict__ se, const float* __restrict__ sk,
                        const float* __restrict__ Wos, const float* __restrict__ bos,
                        const float* __restrict__ Wok, const float* __restrict__ bok,
                        float* __restrict__ comb, float* __restrict__ outp, int n){
  int gid = blockIdx.x * 256 + threadIdx.x;
  int node = gid >> 6, k = gid & 63;
  if (node >= n) return;
  float cv = (k < 32) ? se[node * 32 + k] : sk[node * 32 + (k - 32)];
  comb[node * 64 + k] = cv;
  float s0 = cv * Wos[k * 2], s1 = cv * Wos[k * 2 + 1];
  float q0 = cv * Wok[k * 2], q1 = cv * Wok[k * 2 + 1];
  #pragma unroll
  for (int d = 32; d >= 1; d >>= 1){
    s0 += __shfl_xor(s0, d, 64); s1 += __shfl_xor(s1, d, 64);
    q0 += __shfl_xor(q0, d, 64); q1 += __shfl_xor(q1, d, 64);
  }
  if (k == 0){
    float f0 = (fmaxf(s0 + bos[0], 0.f) + fmaxf(q0 + bok[0], 0.f)) * 0.5f;
    float f1 = (fmaxf(s1 + bos[1], 0.f) + fmaxf(q1 + bok[1], 0.f)) * 0.5f;
    outp[node * 4 + 0] = f0;
    outp[node * 4 + 1] = f1;
  }
}

// ============================ output head 1 (edge_neighbor fused) ============================
__global__ void k_head1(const int* __restrict__ rsS, const int* __restrict__ colS,
                        const int* __restrict__ rsK, const int* __restrict__ colK,
                        const float* __restrict__ comb, const float* __restrict__ x,
                        const float* __restrict__ Wd1, const float* __restrict__ bd1,
                        float* __restrict__ outp, int n){
  int gid = blockIdx.x * 256 + threadIdx.x;
  int node = gid >> 6, k = gid & 63;
  if (node >= n) return;
  float accS = 0.f, accK = 0.f;
  int beg = rsS[node], end = rsS[node + 1];
  for (int j = beg; j < end; ++j){
    int s = colS[j];
    accS += comb[s * 64 + k] * x[s];
  }
  beg = rsK[node]; end = rsK[node + 1];
  for (int j = beg; j < end; ++j){
    int s = colK[j];
    accK += comb[s * 64 + k] * x[s];
  }
  float cd = comb[node * 64 + k] * 0.5f;
  float tv = fmaxf(accS + cd, 0.f) + fmaxf(accK + cd, 0.f);
  float r0 = tv * Wd1[k * 2], r1 = tv * Wd1[k * 2 + 1];
  #pragma unroll
  for (int d = 32; d >= 1; d >>= 1){
    r0 += __shfl_xor(r0, d, 64); r1 += __shfl_xor(r1, d, 64);
  }
  if (k == 0){
    outp[node * 4 + 2] = fmaxf(r0 + bd1[0], 0.f);
    outp[node * 4 + 3] = fmaxf(r1 + bd1[1], 0.f);
  }
}

// ============================ launch ============================

extern "C" void kernel_launch(void* const* d_in, const int* in_sizes, int n_in,
                              void* d_out, int out_size, void* d_ws, size_t ws_size,
                              hipStream_t stream) {
  const float* x      = (const float*)d_in[0];
  const int*   eiS    = (const int*)d_in[1];
  const int*   eiK    = (const int*)d_in[2];
  const float* W_in_src = (const float*)d_in[3];
  const float* b_in_src = (const float*)d_in[4];
  const float* a1_in_src= (const float*)d_in[5];
  const float* a2_in_src= (const float*)d_in[6];
  const float* W_in_snk = (const float*)d_in[7];
  const float* b_in_snk = (const float*)d_in[8];
  const float* a1_in_snk= (const float*)d_in[9];
  const float* a2_in_snk= (const float*)d_in[10];
  const float* W_src  = (const float*)d_in[11];
  const float* b_src  = (const float*)d_in[12];
  const float* a1_src = (const float*)d_in[13];
  const float* a2_src = (const float*)d_in[14];
  const float* W_snk  = (const float*)d_in[15];
  const float* b_snk  = (const float*)d_in[16];
  const float* a1_snk = (const float*)d_in[17];
  const float* a2_snk = (const float*)d_in[18];
  const float* W_o_src= (const float*)d_in[19];
  const float* b_o_src= (const float*)d_in[20];
  const float* W_o_snk= (const float*)d_in[21];
  const float* b_o_snk= (const float*)d_in[22];
  const float* W_d1   = (const float*)d_in[23];
  const float* b_d1   = (const float*)d_in[24];
  float* outp = (float*)d_out;

  const int N = in_sizes[0];       // 100000
  const int E = in_sizes[1] / 2;   // 1600000
  const int L = 5;

  // ---- workspace layout ----
  float* f = (float*)d_ws;
  float* seA = f;  f += (size_t)N * 32;
  float* skA = f;  f += (size_t)N * 32;
  float* hS  = f;  f += (size_t)N * 32;
  float* hK  = f;  f += (size_t)N * 32;   // hS/hK adjacent -> comb aliases them ([N,64])
  float* comb = hS;
  float* a1Sv = f; f += N;
  float* a2Sv = f; f += N;
  float* a1Kv = f; f += N;
  float* a2Kv = f; f += N;
  int* ip = (int*)f;
  int* rsS    = ip; ip += N + 1;
  int* rsK    = ip; ip += N + 1;
  int* colS   = ip; ip += E;
  int* colK   = ip; ip += E;
  int* cursor = ip; ip += N;
  int* bsum   = ip; ip += 256;

  const int TB = 256;
  int gN    = (N + TB - 1) / TB;
  int gE    = (E + TB - 1) / TB;
  int gN32  = (N * 32 + TB - 1) / TB;
  int gN64  = (N * 64 + TB - 1) / TB;
  int nb    = (N + 1023) / 1024;

  // ---- CSR build: source graph ----
  hipLaunchKernelGGL(k_zero,   dim3(gN), dim3(TB), 0, stream, cursor, N);
  hipLaunchKernelGGL(k_count,  dim3(gE), dim3(TB), 0, stream, eiS, cursor, E);
  hipLaunchKernelGGL(k_scan1,  dim3(nb), dim3(TB), 0, stream, cursor, bsum, N);
  hipLaunchKernelGGL(k_scan2,  dim3(1),  dim3(128), 0, stream, bsum, nb, rsS, N);
  hipLaunchKernelGGL(k_scan3,  dim3(nb), dim3(TB), 0, stream, cursor, bsum, rsS, N);
  hipLaunchKernelGGL(k_copy,   dim3(gN), dim3(TB), 0, stream, rsS, cursor, N);
  hipLaunchKernelGGL(k_scatter,dim3(gE), dim3(TB), 0, stream, eiS, cursor, colS, E);
  // ---- CSR build: sink graph ----
  hipLaunchKernelGGL(k_zero,   dim3(gN), dim3(TB), 0, stream, cursor, N);
  hipLaunchKernelGGL(k_count,  dim3(gE), dim3(TB), 0, stream, eiK, cursor, E);
  hipLaunchKernelGGL(k_scan1,  dim3(nb), dim3(TB), 0, stream, cursor, bsum, N);
  hipLaunchKernelGGL(k_scan2,  dim3(1),  dim3(128), 0, stream, bsum, nb, rsK, N);
  hipLaunchKernelGGL(k_scan3,  dim3(nb), dim3(TB), 0, stream, cursor, bsum, rsK, N);
  hipLaunchKernelGGL(k_copy,   dim3(gN), dim3(TB), 0, stream, rsK, cursor, N);
  hipLaunchKernelGGL(k_scatter,dim3(gE), dim3(TB), 0, stream, eiK, cursor, colK, E);

  // ---- layer 1 (input) ----
  hipLaunchKernelGGL(k_gat_l1, dim3(gN32), dim3(TB), 0, stream,
                     rsS, colS, x, W_in_src, b_in_src, a1_in_src, a2_in_src, seA, N);
  hipLaunchKernelGGL(k_gat_l1, dim3(gN32), dim3(TB), 0, stream,
                     rsK, colK, x, W_in_snk, b_in_snk, a1_in_snk, a2_in_snk, skA, N);

  // ---- layers 2..L ----
  for (int i = 0; i < L - 1; ++i){
    hipLaunchKernelGGL(k_linear, dim3(gN32), dim3(TB), 0, stream,
                       seA, skA, W_src + (size_t)i * 1024, W_snk + (size_t)i * 1024,
                       a1_src + i * 32, a2_src + i * 32, a1_snk + i * 32, a2_snk + i * 32,
                       hS, hK, a1Sv, a2Sv, a1Kv, a2Kv, N);
    hipLaunchKernelGGL(k_gat_agg, dim3(gN32), dim3(TB), 0, stream,
                       rsS, colS, hS, a1Sv, a2Sv, b_src + i * 32, seA, N);
    hipLaunchKernelGGL(k_gat_agg, dim3(gN32), dim3(TB), 0, stream,
                       rsK, colK, hK, a1Kv, a2Kv, b_snk + i * 32, skA, N);
  }

  // ---- heads ----
  hipLaunchKernelGGL(k_head0, dim3(gN64), dim3(TB), 0, stream,
                     seA, skA, W_o_src, b_o_src, W_o_snk, b_o_snk, comb, outp, N);
  hipLaunchKernelGGL(k_head1, dim3(gN64), dim3(TB), 0, stream,
                     rsS, colS, rsK, colK, comb, x, W_d1, b_d1, outp, N);
}

// Round 2
// 1446.591 us; speedup vs baseline: 1.2751x; 1.2751x over previous
//
#include <hip/hip_runtime.h>

#define NEG_SLOPE 0.2f
#define PRELU_W 0.1f

__device__ __forceinline__ float d_lrelu(float v){ return v >= 0.f ? v : NEG_SLOPE * v; }
__device__ __forceinline__ float d_prelu(float v){ return v >= 0.f ? v : PRELU_W * v; }

// ============================ CSR build ============================

__global__ void k_zero(int* __restrict__ p, int n){
  int i = blockIdx.x * 256 + threadIdx.x;
  if (i < n) p[i] = 0;
}

__global__ void k_count(const int* __restrict__ ei, int* __restrict__ deg, int E){
  int e = blockIdx.x * 256 + threadIdx.x;
  if (e < E) atomicAdd(&deg[ei[E + e]], 1);
}

// chunk=1024 per block (256 thr x 4)
__global__ void k_scan1(const int* __restrict__ deg, int* __restrict__ bsum, int n){
  int b = blockIdx.x, t = threadIdx.x;
  int base = b * 1024 + t * 4;
  int s = 0;
  #pragma unroll
  for (int k2 = 0; k2 < 4; ++k2){ int i = base + k2; if (i < n) s += deg[i]; }
  #pragma unroll
  for (int d = 32; d >= 1; d >>= 1) s += __shfl_xor(s, d, 64);
  __shared__ int ws[4];
  int lane = t & 63, wid = t >> 6;
  if (lane == 0) ws[wid] = s;
  __syncthreads();
  if (t == 0) bsum[b] = ws[0] + ws[1] + ws[2] + ws[3];
}

// single block, 128 threads: exclusive-scan bsum (nb <= 128), write rs[n]=total
__global__ void k_scan2(int* __restrict__ bsum, int nb, int* __restrict__ rs, int n){
  int t = threadIdx.x;
  int v = (t < nb) ? bsum[t] : 0;
  int x = v;
  int lane = t & 63, wid = t >> 6;
  #pragma unroll
  for (int d = 1; d < 64; d <<= 1){ int y = __shfl_up(x, d, 64); if (lane >= d) x += y; }
  __shared__ int wq[2];
  if (lane == 63) wq[wid] = x;
  __syncthreads();
  if (wid == 1) x += wq[0];
  if (t < nb) bsum[t] = x - v;
  if (t == nb - 1) rs[n] = x;
}

__global__ void k_scan3(const int* __restrict__ deg, const int* __restrict__ bsum,
                        int* __restrict__ rs, int n){
  int b = blockIdx.x, t = threadIdx.x;
  int base = b * 1024 + t * 4;
  int v[4];
  #pragma unroll
  for (int k2 = 0; k2 < 4; ++k2){ int i = base + k2; v[k2] = (i < n) ? deg[i] : 0; }
  int tsum = v[0] + v[1] + v[2] + v[3];
  int x = tsum;
  int lane = t & 63, wid = t >> 6;
  #pragma unroll
  for (int d = 1; d < 64; d <<= 1){ int y = __shfl_up(x, d, 64); if (lane >= d) x += y; }
  __shared__ int ws[4];
  if (lane == 63) ws[wid] = x;
  __syncthreads();
  int woff = 0;
  for (int w = 0; w < wid; ++w) woff += ws[w];
  int run = bsum[b] + woff + (x - tsum);
  #pragma unroll
  for (int k2 = 0; k2 < 4; ++k2){ int i = base + k2; if (i < n) rs[i] = run; run += v[k2]; }
}

__global__ void k_copy(const int* __restrict__ a, int* __restrict__ b, int n){
  int i = blockIdx.x * 256 + threadIdx.x;
  if (i < n) b[i] = a[i];
}

__global__ void k_scatter(const int* __restrict__ ei, int* __restrict__ cur,
                          int* __restrict__ col, int E){
  int e = blockIdx.x * 256 + threadIdx.x;
  if (e < E){
    int s = ei[e], d = ei[E + e];
    int p = atomicAdd(&cur[d], 1);
    col[p] = s;
  }
}

// ============================ GAT layer 1 (x is [N,1]) ============================
// h[s] = x[s]*W  => out[d] = (sum_j alpha_j x[s_j]) * W + b.
// Lane-cooperative: lane k loads col/x for edge j0+k, inner loop is pure compute.
__global__ void k_gat_l1(const int* __restrict__ rs, const int* __restrict__ col,
                         const float* __restrict__ x,
                         const float* __restrict__ W, const float* __restrict__ bias,
                         const float* __restrict__ a1v, const float* __restrict__ a2v,
                         float* __restrict__ outp, int n){
  int gid = blockIdx.x * 256 + threadIdx.x;
  int node = gid >> 5, k = gid & 31;
  if (node >= n) return;
  float Wk = W[k];
  float p1 = Wk * a1v[k], p2 = Wk * a2v[k];
  #pragma unroll
  for (int d = 16; d >= 1; d >>= 1){ p1 += __shfl_xor(p1, d, 32); p2 += __shfl_xor(p2, d, 32); }
  float a2d = x[node] * p2;
  int beg = rs[node], end = rs[node + 1];
  float denom = 0.f, accx = 0.f;
  for (int j0 = beg; j0 < end; j0 += 32){
    int idx = j0 + k;
    float xl = 0.f;
    if (idx < end) xl = x[col[idx]];
    int m = min(32, end - j0);
    #pragma unroll 4
    for (int e = 0; e < m; ++e){
      float xs = __shfl(xl, e, 32);
      float w = __expf(d_lrelu(xs * p1 + a2d));
      denom += w;
      accx += w * xs;
    }
  }
  float o = accx / (denom + 1e-16f) * Wk + bias[k];
  outp[node * 32 + k] = d_prelu(o);
}

// ============================ per-layer linear ============================
__global__ void k_linear(const float* __restrict__ se, const float* __restrict__ sk,
                         const float* __restrict__ WS, const float* __restrict__ WK,
                         const float* __restrict__ a1S, const float* __restrict__ a2S,
                         const float* __restrict__ a1K, const float* __restrict__ a2K,
                         float* __restrict__ hS, float* __restrict__ hK,
                         float* __restrict__ oa1S, float* __restrict__ oa2S,
                         float* __restrict__ oa1K, float* __restrict__ oa2K, int n){
  __shared__ float sWS[1024], sWK[1024], sa[128];
  int t = threadIdx.x;
  for (int i = t; i < 1024; i += 256){ sWS[i] = WS[i]; sWK[i] = WK[i]; }
  if (t < 32){ sa[t] = a1S[t]; sa[32 + t] = a2S[t]; sa[64 + t] = a1K[t]; sa[96 + t] = a2K[t]; }
  __syncthreads();
  int gid = blockIdx.x * 256 + t;
  int node = gid >> 5, k = gid & 31;
  if (node >= n) return;
  float c = se[node * 32 + k] + sk[node * 32 + k];
  float hs = 0.f, hk = 0.f;
  #pragma unroll
  for (int m = 0; m < 32; ++m){
    float cm = __shfl(c, m, 32);
    hs += cm * sWS[m * 32 + k];
    hk += cm * sWK[m * 32 + k];
  }
  hS[node * 32 + k] = hs;
  hK[node * 32 + k] = hk;
  float r1 = hs * sa[k], r2 = hs * sa[32 + k], r3 = hk * sa[64 + k], r4 = hk * sa[96 + k];
  #pragma unroll
  for (int d = 16; d >= 1; d >>= 1){
    r1 += __shfl_xor(r1, d, 32); r2 += __shfl_xor(r2, d, 32);
    r3 += __shfl_xor(r3, d, 32); r4 += __shfl_xor(r4, d, 32);
  }
  if (k == 0){ oa1S[node] = r1; oa2S[node] = r2; oa1K[node] = r3; oa2K[node] = r4; }
}

// ============================ generic GAT aggregation ============================
// Lane-cooperative batch: lane k prefetches col + a1 for edge j0+k, then the
// inner loop's h-row gathers are all independent (register-fed addresses).
__global__ void k_gat_agg(const int* __restrict__ rs, const int* __restrict__ col,
                          const float* __restrict__ h,
                          const float* __restrict__ a1, const float* __restrict__ a2,
                          const float* __restrict__ bias,
                          float* __restrict__ outp, int n){
  int gid = blockIdx.x * 256 + threadIdx.x;
  int node = gid >> 5, k = gid & 31;
  if (node >= n) return;
  float a2d = a2[node];
  int beg = rs[node], end = rs[node + 1];
  float denom = 0.f, acc = 0.f;
  for (int j0 = beg; j0 < end; j0 += 32){
    int idx = j0 + k;
    int sl = 0; float a1l = 0.f;
    if (idx < end){ sl = col[idx]; a1l = a1[sl]; }
    int m = min(32, end - j0);
    #pragma unroll 4
    for (int e = 0; e < m; ++e){
      int s = __shfl(sl, e, 32);
      float ev = d_lrelu(__shfl(a1l, e, 32) + a2d);
      float w = __expf(ev);
      denom += w;
      acc += w * h[(size_t)s * 32 + k];
    }
  }
  float o = acc / (denom + 1e-16f) + bias[k];
  outp[node * 32 + k] = d_prelu(o);
}

// ============================ output head 0 ============================
__global__ void k_head0(const float* __restrict__ se, const float* __restrict__ sk,
                        const float* __restrict__ Wos, const float* __restrict__ bos,
                        const float* __restrict__ Wok, const float* __restrict__ bok,
                        float* __restrict__ comb, float* __restrict__ outp, int n){
  int gid = blockIdx.x * 256 + threadIdx.x;
  int node = gid >> 6, k = gid & 63;
  if (node >= n) return;
  float cv = (k < 32) ? se[node * 32 + k] : sk[node * 32 + (k - 32)];
  comb[node * 64 + k] = cv;
  float s0 = cv * Wos[k * 2], s1 = cv * Wos[k * 2 + 1];
  float q0 = cv * Wok[k * 2], q1 = cv * Wok[k * 2 + 1];
  #pragma unroll
  for (int d = 32; d >= 1; d >>= 1){
    s0 += __shfl_xor(s0, d, 64); s1 += __shfl_xor(s1, d, 64);
    q0 += __shfl_xor(q0, d, 64); q1 += __shfl_xor(q1, d, 64);
  }
  if (k == 0){
    float f0 = (fmaxf(s0 + bos[0], 0.f) + fmaxf(q0 + bok[0], 0.f)) * 0.5f;
    float f1 = (fmaxf(s1 + bos[1], 0.f) + fmaxf(q1 + bok[1], 0.f)) * 0.5f;
    outp[node * 4 + 0] = f0;
    outp[node * 4 + 1] = f1;
  }
}

// ============================ output head 1 (edge_neighbor fused) ============================
// Lane-cooperative: lane k prefetches col + x for edge j0+k (64-wide batch);
// inner-loop comb-row gathers are independent.
__global__ void k_head1(const int* __restrict__ rsS, const int* __restrict__ colS,
                        const int* __restrict__ rsK, const int* __restrict__ colK,
                        const float* __restrict__ comb, const float* __restrict__ x,
                        const float* __restrict__ Wd1, const float* __restrict__ bd1,
                        float* __restrict__ outp, int n){
  int gid = blockIdx.x * 256 + threadIdx.x;
  int node = gid >> 6, k = gid & 63;
  if (node >= n) return;
  float accS = 0.f, accK = 0.f;
  {
    int beg = rsS[node], end = rsS[node + 1];
    for (int j0 = beg; j0 < end; j0 += 64){
      int idx = j0 + k;
      int sl = 0; float xl = 0.f;
      if (idx < end){ sl = colS[idx]; xl = x[sl]; }
      int m = min(64, end - j0);
      #pragma unroll 4
      for (int e = 0; e < m; ++e){
        int s = __shfl(sl, e, 64);
        float xs = __shfl(xl, e, 64);
        accS += comb[(size_t)s * 64 + k] * xs;
      }
    }
  }
  {
    int beg = rsK[node], end = rsK[node + 1];
    for (int j0 = beg; j0 < end; j0 += 64){
      int idx = j0 + k;
      int sl = 0; float xl = 0.f;
      if (idx < end){ sl = colK[idx]; xl = x[sl]; }
      int m = min(64, end - j0);
      #pragma unroll 4
      for (int e = 0; e < m; ++e){
        int s = __shfl(sl, e, 64);
        float xs = __shfl(xl, e, 64);
        accK += comb[(size_t)s * 64 + k] * xs;
      }
    }
  }
  float cd = comb[(size_t)node * 64 + k] * 0.5f;
  float tv = fmaxf(accS + cd, 0.f) + fmaxf(accK + cd, 0.f);
  float r0 = tv * Wd1[k * 2], r1 = tv * Wd1[k * 2 + 1];
  #pragma unroll
  for (int d = 32; d >= 1; d >>= 1){
    r0 += __shfl_xor(r0, d, 64); r1 += __shfl_xor(r1, d, 64);
  }
  if (k == 0){
    outp[node * 4 + 2] = fmaxf(r0 + bd1[0], 0.f);
    outp[node * 4 + 3] = fmaxf(r1 + bd1[1], 0.f);
  }
}

// ============================ launch ============================

extern "C" void kernel_launch(void* const* d_in, const int* in_sizes, int n_in,
                              void* d_out, int out_size, void* d_ws, size_t ws_size,
                              hipStream_t stream) {
  const float* x      = (const float*)d_in[0];
  const int*   eiS    = (const int*)d_in[1];
  const int*   eiK    = (const int*)d_in[2];
  const float* W_in_src = (const float*)d_in[3];
  const float* b_in_src = (const float*)d_in[4];
  const float* a1_in_src= (const float*)d_in[5];
  const float* a2_in_src= (const float*)d_in[6];
  const float* W_in_snk = (const float*)d_in[7];
  const float* b_in_snk = (const float*)d_in[8];
  const float* a1_in_snk= (const float*)d_in[9];
  const float* a2_in_snk= (const float*)d_in[10];
  const float* W_src  = (const float*)d_in[11];
  const float* b_src  = (const float*)d_in[12];
  const float* a1_src = (const float*)d_in[13];
  const float* a2_src = (const float*)d_in[14];
  const float* W_snk  = (const float*)d_in[15];
  const float* b_snk  = (const float*)d_in[16];
  const float* a1_snk = (const float*)d_in[17];
  const float* a2_snk = (const float*)d_in[18];
  const float* W_o_src= (const float*)d_in[19];
  const float* b_o_src= (const float*)d_in[20];
  const float* W_o_snk= (const float*)d_in[21];
  const float* b_o_snk= (const float*)d_in[22];
  const float* W_d1   = (const float*)d_in[23];
  const float* b_d1   = (const float*)d_in[24];
  float* outp = (float*)d_out;

  const int N = in_sizes[0];       // 100000
  const int E = in_sizes[1] / 2;   // 1600000
  const int L = 5;

  // ---- workspace layout ----
  float* f = (float*)d_ws;
  float* seA = f;  f += (size_t)N * 32;
  float* skA = f;  f += (size_t)N * 32;
  float* hS  = f;  f += (size_t)N * 32;
  float* hK  = f;  f += (size_t)N * 32;   // hS/hK adjacent -> comb aliases them ([N,64])
  float* comb = hS;
  float* a1Sv = f; f += N;
  float* a2Sv = f; f += N;
  float* a1Kv = f; f += N;
  float* a2Kv = f; f += N;
  int* ip = (int*)f;
  int* rsS    = ip; ip += N + 1;
  int* rsK    = ip; ip += N + 1;
  int* colS   = ip; ip += E;
  int* colK   = ip; ip += E;
  int* cursor = ip; ip += N;
  int* bsum   = ip; ip += 256;

  const int TB = 256;
  int gN    = (N + TB - 1) / TB;
  int gE    = (E + TB - 1) / TB;
  int gN32  = (N * 32 + TB - 1) / TB;
  int gN64  = (N * 64 + TB - 1) / TB;
  int nb    = (N + 1023) / 1024;

  // ---- CSR build: source graph ----
  hipLaunchKernelGGL(k_zero,   dim3(gN), dim3(TB), 0, stream, cursor, N);
  hipLaunchKernelGGL(k_count,  dim3(gE), dim3(TB), 0, stream, eiS, cursor, E);
  hipLaunchKernelGGL(k_scan1,  dim3(nb), dim3(TB), 0, stream, cursor, bsum, N);
  hipLaunchKernelGGL(k_scan2,  dim3(1),  dim3(128), 0, stream, bsum, nb, rsS, N);
  hipLaunchKernelGGL(k_scan3,  dim3(nb), dim3(TB), 0, stream, cursor, bsum, rsS, N);
  hipLaunchKernelGGL(k_copy,   dim3(gN), dim3(TB), 0, stream, rsS, cursor, N);
  hipLaunchKernelGGL(k_scatter,dim3(gE), dim3(TB), 0, stream, eiS, cursor, colS, E);
  // ---- CSR build: sink graph ----
  hipLaunchKernelGGL(k_zero,   dim3(gN), dim3(TB), 0, stream, cursor, N);
  hipLaunchKernelGGL(k_count,  dim3(gE), dim3(TB), 0, stream, eiK, cursor, E);
  hipLaunchKernelGGL(k_scan1,  dim3(nb), dim3(TB), 0, stream, cursor, bsum, N);
  hipLaunchKernelGGL(k_scan2,  dim3(1),  dim3(128), 0, stream, bsum, nb, rsK, N);
  hipLaunchKernelGGL(k_scan3,  dim3(nb), dim3(TB), 0, stream, cursor, bsum, rsK, N);
  hipLaunchKernelGGL(k_copy,   dim3(gN), dim3(TB), 0, stream, rsK, cursor, N);
  hipLaunchKernelGGL(k_scatter,dim3(gE), dim3(TB), 0, stream, eiK, cursor, colK, E);

  // ---- layer 1 (input) ----
  hipLaunchKernelGGL(k_gat_l1, dim3(gN32), dim3(TB), 0, stream,
                     rsS, colS, x, W_in_src, b_in_src, a1_in_src, a2_in_src, seA, N);
  hipLaunchKernelGGL(k_gat_l1, dim3(gN32), dim3(TB), 0, stream,
                     rsK, colK, x, W_in_snk, b_in_snk, a1_in_snk, a2_in_snk, skA, N);

  // ---- layers 2..L ----
  for (int i = 0; i < L - 1; ++i){
    hipLaunchKernelGGL(k_linear, dim3(gN32), dim3(TB), 0, stream,
                       seA, skA, W_src + (size_t)i * 1024, W_snk + (size_t)i * 1024,
                       a1_src + i * 32, a2_src + i * 32, a1_snk + i * 32, a2_snk + i * 32,
                       hS, hK, a1Sv, a2Sv, a1Kv, a2Kv, N);
    hipLaunchKernelGGL(k_gat_agg, dim3(gN32), dim3(TB), 0, stream,
                       rsS, colS, hS, a1Sv, a2Sv, b_src + i * 32, seA, N);
    hipLaunchKernelGGL(k_gat_agg, dim3(gN32), dim3(TB), 0, stream,
                       rsK, colK, hK, a1Kv, a2Kv, b_snk + i * 32, skA, N);
  }

  // ---- heads ----
  hipLaunchKernelGGL(k_head0, dim3(gN64), dim3(TB), 0, stream,
                     seA, skA, W_o_src, b_o_src, W_o_snk, b_o_snk, comb, outp, N);
  hipLaunchKernelGGL(k_head1, dim3(gN64), dim3(TB), 0, stream,
                     rsS, colS, rsK, colK, comb, x, W_d1, b_d1, outp, N);
}

// Round 3
// 1411.695 us; speedup vs baseline: 1.3066x; 1.0247x over previous
//
#include <hip/hip_runtime.h>

#define NEG_SLOPE 0.2f
#define PRELU_W 0.1f

__device__ __forceinline__ float d_lrelu(float v){ return v >= 0.f ? v : NEG_SLOPE * v; }
__device__ __forceinline__ float d_prelu(float v){ return v >= 0.f ? v : PRELU_W * v; }

// bf16 helpers (round-to-nearest-even), no header dependency
__device__ __forceinline__ unsigned short f2bf(float f){
  unsigned int u = __builtin_bit_cast(unsigned int, f);
  unsigned int r = (u + 0x7fffu + ((u >> 16) & 1u)) >> 16;
  return (unsigned short)r;
}
__device__ __forceinline__ float bf2f(unsigned short h){
  unsigned int u = ((unsigned int)h) << 16;
  return __builtin_bit_cast(float, u);
}

// ============================ CSR build ============================

__global__ void k_zero(int* __restrict__ p, int n){
  int i = blockIdx.x * 256 + threadIdx.x;
  if (i < n) p[i] = 0;
}

__global__ void k_count(const int* __restrict__ ei, int* __restrict__ deg, int E){
  int e = blockIdx.x * 256 + threadIdx.x;
  if (e < E) atomicAdd(&deg[ei[E + e]], 1);
}

// chunk=1024 per block (256 thr x 4)
__global__ void k_scan1(const int* __restrict__ deg, int* __restrict__ bsum, int n){
  int b = blockIdx.x, t = threadIdx.x;
  int base = b * 1024 + t * 4;
  int s = 0;
  #pragma unroll
  for (int k2 = 0; k2 < 4; ++k2){ int i = base + k2; if (i < n) s += deg[i]; }
  #pragma unroll
  for (int d = 32; d >= 1; d >>= 1) s += __shfl_xor(s, d, 64);
  __shared__ int ws[4];
  int lane = t & 63, wid = t >> 6;
  if (lane == 0) ws[wid] = s;
  __syncthreads();
  if (t == 0) bsum[b] = ws[0] + ws[1] + ws[2] + ws[3];
}

// single block, 128 threads: exclusive-scan bsum (nb <= 128), write rs[n]=total
__global__ void k_scan2(int* __restrict__ bsum, int nb, int* __restrict__ rs, int n){
  int t = threadIdx.x;
  int v = (t < nb) ? bsum[t] : 0;
  int x = v;
  int lane = t & 63, wid = t >> 6;
  #pragma unroll
  for (int d = 1; d < 64; d <<= 1){ int y = __shfl_up(x, d, 64); if (lane >= d) x += y; }
  __shared__ int wq[2];
  if (lane == 63) wq[wid] = x;
  __syncthreads();
  if (wid == 1) x += wq[0];
  if (t < nb) bsum[t] = x - v;
  if (t == nb - 1) rs[n] = x;
}

__global__ void k_scan3(const int* __restrict__ deg, const int* __restrict__ bsum,
                        int* __restrict__ rs, int n){
  int b = blockIdx.x, t = threadIdx.x;
  int base = b * 1024 + t * 4;
  int v[4];
  #pragma unroll
  for (int k2 = 0; k2 < 4; ++k2){ int i = base + k2; v[k2] = (i < n) ? deg[i] : 0; }
  int tsum = v[0] + v[1] + v[2] + v[3];
  int x = tsum;
  int lane = t & 63, wid = t >> 6;
  #pragma unroll
  for (int d = 1; d < 64; d <<= 1){ int y = __shfl_up(x, d, 64); if (lane >= d) x += y; }
  __shared__ int ws[4];
  if (lane == 63) ws[wid] = x;
  __syncthreads();
  int woff = 0;
  for (int w = 0; w < wid; ++w) woff += ws[w];
  int run = bsum[b] + woff + (x - tsum);
  #pragma unroll
  for (int k2 = 0; k2 < 4; ++k2){ int i = base + k2; if (i < n) rs[i] = run; run += v[k2]; }
}

__global__ void k_copy(const int* __restrict__ a, int* __restrict__ b, int n){
  int i = blockIdx.x * 256 + threadIdx.x;
  if (i < n) b[i] = a[i];
}

__global__ void k_scatter(const int* __restrict__ ei, int* __restrict__ cur,
                          int* __restrict__ col, int E){
  int e = blockIdx.x * 256 + threadIdx.x;
  if (e < E){
    int s = ei[e], d = ei[E + e];
    int p = atomicAdd(&cur[d], 1);
    col[p] = s;
  }
}

// ============================ GAT layer 1 (x is [N,1]) ============================
// h[s] = x[s]*W  => out[d] = (sum_j alpha_j x[s_j]) * W + b.
// Fully per-lane accumulation (scalar softmax invariant in k), fused both graphs.
__global__ void k_gat_l1(const int* __restrict__ rsA, const int* __restrict__ colA,
                         const int* __restrict__ rsB, const int* __restrict__ colB,
                         const float* __restrict__ x,
                         const float* __restrict__ WA, const float* __restrict__ bA,
                         const float* __restrict__ a1A, const float* __restrict__ a2A,
                         const float* __restrict__ WB, const float* __restrict__ bB,
                         const float* __restrict__ a1B, const float* __restrict__ a2B,
                         float* __restrict__ outA, float* __restrict__ outB, int n){
  bool g = (blockIdx.y != 0);
  const int* rs  = g ? rsB  : rsA;
  const int* col = g ? colB : colA;
  const float* W = g ? WB : WA;  const float* bias = g ? bB : bA;
  const float* a1 = g ? a1B : a1A; const float* a2 = g ? a2B : a2A;
  float* outp = g ? outB : outA;

  int gid = blockIdx.x * 256 + threadIdx.x;
  int node = gid >> 5, k = gid & 31;
  if (node >= n) return;
  float Wk = W[k];
  float p1 = Wk * a1[k], p2 = Wk * a2[k];
  #pragma unroll
  for (int d = 16; d >= 1; d >>= 1){ p1 += __shfl_xor(p1, d, 32); p2 += __shfl_xor(p2, d, 32); }
  float a2d = x[node] * p2;
  int beg = rs[node], end = rs[node + 1];
  float denom = 0.f, accx = 0.f;
  #pragma unroll 2
  for (int idx = beg + k; idx < end; idx += 32){
    float xs = x[col[idx]];
    float w = __expf(d_lrelu(xs * p1 + a2d));
    denom += w;
    accx += w * xs;
  }
  #pragma unroll
  for (int d = 16; d >= 1; d >>= 1){
    denom += __shfl_xor(denom, d, 32);
    accx  += __shfl_xor(accx,  d, 32);
  }
  float o = accx / (denom + 1e-16f) * Wk + bias[k];
  outp[node * 32 + k] = d_prelu(o);
}

// ============================ per-layer linear ============================
// c = se+sk ; hS = c@WS ; hK = c@WK (stored bf16); attention dots for both graphs.
__global__ void k_linear(const float* __restrict__ se, const float* __restrict__ sk,
                         const float* __restrict__ WS, const float* __restrict__ WK,
                         const float* __restrict__ a1S, const float* __restrict__ a2S,
                         const float* __restrict__ a1K, const float* __restrict__ a2K,
                         unsigned short* __restrict__ hS, unsigned short* __restrict__ hK,
                         float* __restrict__ oa1S, float* __restrict__ oa2S,
                         float* __restrict__ oa1K, float* __restrict__ oa2K, int n){
  __shared__ float sWS[1024], sWK[1024], sa[128];
  int t = threadIdx.x;
  for (int i = t; i < 1024; i += 256){ sWS[i] = WS[i]; sWK[i] = WK[i]; }
  if (t < 32){ sa[t] = a1S[t]; sa[32 + t] = a2S[t]; sa[64 + t] = a1K[t]; sa[96 + t] = a2K[t]; }
  __syncthreads();
  int gid = blockIdx.x * 256 + t;
  int node = gid >> 5, k = gid & 31;
  if (node >= n) return;
  float c = se[node * 32 + k] + sk[node * 32 + k];
  float hs = 0.f, hk = 0.f;
  #pragma unroll
  for (int m = 0; m < 32; ++m){
    float cm = __shfl(c, m, 32);
    hs += cm * sWS[m * 32 + k];
    hk += cm * sWK[m * 32 + k];
  }
  hS[node * 32 + k] = f2bf(hs);
  hK[node * 32 + k] = f2bf(hk);
  float r1 = hs * sa[k], r2 = hs * sa[32 + k], r3 = hk * sa[64 + k], r4 = hk * sa[96 + k];
  #pragma unroll
  for (int d = 16; d >= 1; d >>= 1){
    r1 += __shfl_xor(r1, d, 32); r2 += __shfl_xor(r2, d, 32);
    r3 += __shfl_xor(r3, d, 32); r4 += __shfl_xor(r4, d, 32);
  }
  if (k == 0){ oa1S[node] = r1; oa2S[node] = r2; oa1K[node] = r3; oa2K[node] = r4; }
}

// ============================ generic GAT aggregation ============================
// Prefetch lane computes the per-edge softmax weight once (a2d is group-uniform);
// denominator is a per-lane partial. Inner loop: shfl(s), shfl(w), bf16 gather, fma.
// Both graphs fused via blockIdx.y.
__global__ void k_gat_agg(const int* __restrict__ rsA, const int* __restrict__ colA,
                          const unsigned short* __restrict__ hA,
                          const float* __restrict__ a1A, const float* __restrict__ a2A,
                          const float* __restrict__ bA, float* __restrict__ outA,
                          const int* __restrict__ rsB, const int* __restrict__ colB,
                          const unsigned short* __restrict__ hB,
                          const float* __restrict__ a1B, const float* __restrict__ a2B,
                          const float* __restrict__ bB, float* __restrict__ outB, int n){
  bool g = (blockIdx.y != 0);
  const int* rs  = g ? rsB  : rsA;
  const int* col = g ? colB : colA;
  const unsigned short* h = g ? hB : hA;
  const float* a1 = g ? a1B : a1A;
  const float* a2 = g ? a2B : a2A;
  const float* bias = g ? bB : bA;
  float* outp = g ? outB : outA;

  int gid = blockIdx.x * 256 + threadIdx.x;
  int node = gid >> 5, k = gid & 31;
  if (node >= n) return;
  float a2d = a2[node];
  int beg = rs[node], end = rs[node + 1];
  float dpart = 0.f, acc = 0.f;
  for (int j0 = beg; j0 < end; j0 += 32){
    int idx = j0 + k;
    int sl = 0; float wl = 0.f;
    if (idx < end){
      sl = col[idx];
      wl = __expf(d_lrelu(a1[sl] + a2d));
    }
    dpart += wl;
    int m = min(32, end - j0);
    #pragma unroll 8
    for (int e = 0; e < m; ++e){
      int s = __shfl(sl, e, 32);
      float w = __shfl(wl, e, 32);
      acc += w * bf2f(h[(size_t)s * 32 + k]);
    }
  }
  float denom = dpart;
  #pragma unroll
  for (int d = 16; d >= 1; d >>= 1) denom += __shfl_xor(denom, d, 32);
  float o = acc / (denom + 1e-16f) + bias[k];
  outp[node * 32 + k] = d_prelu(o);
}

// ============================ output head 0 ============================
// comb = [se|sk] stored bf16; final_dim0 = (relu(comb@Wos+bos)+relu(comb@Wok+bok))/2
__global__ void k_head0(const float* __restrict__ se, const float* __restrict__ sk,
                        const float* __restrict__ Wos, const float* __restrict__ bos,
                        const float* __restrict__ Wok, const float* __restrict__ bok,
                        unsigned short* __restrict__ comb, float* __restrict__ outp, int n){
  int gid = blockIdx.x * 256 + threadIdx.x;
  int node = gid >> 6, k = gid & 63;
  if (node >= n) return;
  float cv = (k < 32) ? se[node * 32 + k] : sk[node * 32 + (k - 32)];
  comb[(size_t)node * 64 + k] = f2bf(cv);
  float s0 = cv * Wos[k * 2], s1 = cv * Wos[k * 2 + 1];
  float q0 = cv * Wok[k * 2], q1 = cv * Wok[k * 2 + 1];
  #pragma unroll
  for (int d = 32; d >= 1; d >>= 1){
    s0 += __shfl_xor(s0, d, 64); s1 += __shfl_xor(s1, d, 64);
    q0 += __shfl_xor(q0, d, 64); q1 += __shfl_xor(q1, d, 64);
  }
  if (k == 0){
    float f0 = (fmaxf(s0 + bos[0], 0.f) + fmaxf(q0 + bok[0], 0.f)) * 0.5f;
    float f1 = (fmaxf(s1 + bos[1], 0.f) + fmaxf(q1 + bok[1], 0.f)) * 0.5f;
    outp[node * 4 + 0] = f0;
    outp[node * 4 + 1] = f1;
  }
}

// ============================ output head 1 (edge_neighbor fused) ============================
// Lane-cooperative prefetch of (col, x); bf16 comb gathers, unroll 8.
__global__ void k_head1(const int* __restrict__ rsS, const int* __restrict__ colS,
                        const int* __restrict__ rsK, const int* __restrict__ colK,
                        const unsigned short* __restrict__ comb, const float* __restrict__ x,
                        const float* __restrict__ Wd1, const float* __restrict__ bd1,
                        float* __restrict__ outp, int n){
  int gid = blockIdx.x * 256 + threadIdx.x;
  int node = gid >> 6, k = gid & 63;
  if (node >= n) return;
  float accS = 0.f, accK = 0.f;
  {
    int beg = rsS[node], end = rsS[node + 1];
    for (int j0 = beg; j0 < end; j0 += 64){
      int idx = j0 + k;
      int sl = 0; float xl = 0.f;
      if (idx < end){ sl = colS[idx]; xl = x[sl]; }
      int m = min(64, end - j0);
      #pragma unroll 8
      for (int e = 0; e < m; ++e){
        int s = __shfl(sl, e, 64);
        float xs = __shfl(xl, e, 64);
        accS += xs * bf2f(comb[(size_t)s * 64 + k]);
      }
    }
  }
  {
    int beg = rsK[node], end = rsK[node + 1];
    for (int j0 = beg; j0 < end; j0 += 64){
      int idx = j0 + k;
      int sl = 0; float xl = 0.f;
      if (idx < end){ sl = colK[idx]; xl = x[sl]; }
      int m = min(64, end - j0);
      #pragma unroll 8
      for (int e = 0; e < m; ++e){
        int s = __shfl(sl, e, 64);
        float xs = __shfl(xl, e, 64);
        accK += xs * bf2f(comb[(size_t)s * 64 + k]);
      }
    }
  }
  float cd = bf2f(comb[(size_t)node * 64 + k]) * 0.5f;
  float tv = fmaxf(accS + cd, 0.f) + fmaxf(accK + cd, 0.f);
  float r0 = tv * Wd1[k * 2], r1 = tv * Wd1[k * 2 + 1];
  #pragma unroll
  for (int d = 32; d >= 1; d >>= 1){
    r0 += __shfl_xor(r0, d, 64); r1 += __shfl_xor(r1, d, 64);
  }
  if (k == 0){
    outp[node * 4 + 2] = fmaxf(r0 + bd1[0], 0.f);
    outp[node * 4 + 3] = fmaxf(r1 + bd1[1], 0.f);
  }
}

// ============================ launch ============================

extern "C" void kernel_launch(void* const* d_in, const int* in_sizes, int n_in,
                              void* d_out, int out_size, void* d_ws, size_t ws_size,
                              hipStream_t stream) {
  const float* x      = (const float*)d_in[0];
  const int*   eiS    = (const int*)d_in[1];
  const int*   eiK    = (const int*)d_in[2];
  const float* W_in_src = (const float*)d_in[3];
  const float* b_in_src = (const float*)d_in[4];
  const float* a1_in_src= (const float*)d_in[5];
  const float* a2_in_src= (const float*)d_in[6];
  const float* W_in_snk = (const float*)d_in[7];
  const float* b_in_snk = (const float*)d_in[8];
  const float* a1_in_snk= (const float*)d_in[9];
  const float* a2_in_snk= (const float*)d_in[10];
  const float* W_src  = (const float*)d_in[11];
  const float* b_src  = (const float*)d_in[12];
  const float* a1_src = (const float*)d_in[13];
  const float* a2_src = (const float*)d_in[14];
  const float* W_snk  = (const float*)d_in[15];
  const float* b_snk  = (const float*)d_in[16];
  const float* a1_snk = (const float*)d_in[17];
  const float* a2_snk = (const float*)d_in[18];
  const float* W_o_src= (const float*)d_in[19];
  const float* b_o_src= (const float*)d_in[20];
  const float* W_o_snk= (const float*)d_in[21];
  const float* b_o_snk= (const float*)d_in[22];
  const float* W_d1   = (const float*)d_in[23];
  const float* b_d1   = (const float*)d_in[24];
  float* outp = (float*)d_out;

  const int N = in_sizes[0];       // 100000
  const int E = in_sizes[1] / 2;   // 1600000
  const int L = 5;

  // ---- workspace layout: floats, then ints, then ushorts ----
  float* f = (float*)d_ws;
  float* seA = f;  f += (size_t)N * 32;
  float* skA = f;  f += (size_t)N * 32;
  float* a1Sv = f; f += N;
  float* a2Sv = f; f += N;
  float* a1Kv = f; f += N;
  float* a2Kv = f; f += N;
  int* ip = (int*)f;
  int* rsS    = ip; ip += N + 1;
  int* rsK    = ip; ip += N + 1;
  int* colS   = ip; ip += E;
  int* colK   = ip; ip += E;
  int* cursor = ip; ip += N;
  int* bsum   = ip; ip += 256;
  unsigned short* us = (unsigned short*)ip;
  unsigned short* hS   = us; us += (size_t)N * 32;
  unsigned short* hK   = us; us += (size_t)N * 32;
  unsigned short* comb = us; us += (size_t)N * 64;

  const int TB = 256;
  int gN    = (N + TB - 1) / TB;
  int gE    = (E + TB - 1) / TB;
  int gN32  = (N * 32 + TB - 1) / TB;
  int gN64  = (N * 64 + TB - 1) / TB;
  int nb    = (N + 1023) / 1024;

  // ---- CSR build: source graph ----
  hipLaunchKernelGGL(k_zero,   dim3(gN), dim3(TB), 0, stream, cursor, N);
  hipLaunchKernelGGL(k_count,  dim3(gE), dim3(TB), 0, stream, eiS, cursor, E);
  hipLaunchKernelGGL(k_scan1,  dim3(nb), dim3(TB), 0, stream, cursor, bsum, N);
  hipLaunchKernelGGL(k_scan2,  dim3(1),  dim3(128), 0, stream, bsum, nb, rsS, N);
  hipLaunchKernelGGL(k_scan3,  dim3(nb), dim3(TB), 0, stream, cursor, bsum, rsS, N);
  hipLaunchKernelGGL(k_copy,   dim3(gN), dim3(TB), 0, stream, rsS, cursor, N);
  hipLaunchKernelGGL(k_scatter,dim3(gE), dim3(TB), 0, stream, eiS, cursor, colS, E);
  // ---- CSR build: sink graph ----
  hipLaunchKernelGGL(k_zero,   dim3(gN), dim3(TB), 0, stream, cursor, N);
  hipLaunchKernelGGL(k_count,  dim3(gE), dim3(TB), 0, stream, eiK, cursor, E);
  hipLaunchKernelGGL(k_scan1,  dim3(nb), dim3(TB), 0, stream, cursor, bsum, N);
  hipLaunchKernelGGL(k_scan2,  dim3(1),  dim3(128), 0, stream, bsum, nb, rsK, N);
  hipLaunchKernelGGL(k_scan3,  dim3(nb), dim3(TB), 0, stream, cursor, bsum, rsK, N);
  hipLaunchKernelGGL(k_copy,   dim3(gN), dim3(TB), 0, stream, rsK, cursor, N);
  hipLaunchKernelGGL(k_scatter,dim3(gE), dim3(TB), 0, stream, eiK, cursor, colK, E);

  // ---- layer 1 (input), both graphs fused via grid.y ----
  hipLaunchKernelGGL(k_gat_l1, dim3(gN32, 2), dim3(TB), 0, stream,
                     rsS, colS, rsK, colK, x,
                     W_in_src, b_in_src, a1_in_src, a2_in_src,
                     W_in_snk, b_in_snk, a1_in_snk, a2_in_snk,
                     seA, skA, N);

  // ---- layers 2..L ----
  for (int i = 0; i < L - 1; ++i){
    hipLaunchKernelGGL(k_linear, dim3(gN32), dim3(TB), 0, stream,
                       seA, skA, W_src + (size_t)i * 1024, W_snk + (size_t)i * 1024,
                       a1_src + i * 32, a2_src + i * 32, a1_snk + i * 32, a2_snk + i * 32,
                       hS, hK, a1Sv, a2Sv, a1Kv, a2Kv, N);
    hipLaunchKernelGGL(k_gat_agg, dim3(gN32, 2), dim3(TB), 0, stream,
                       rsS, colS, hS, a1Sv, a2Sv, b_src + i * 32, seA,
                       rsK, colK, hK, a1Kv, a2Kv, b_snk + i * 32, skA, N);
  }

  // ---- heads ----
  hipLaunchKernelGGL(k_head0, dim3(gN64), dim3(TB), 0, stream,
                     seA, skA, W_o_src, b_o_src, W_o_snk, b_o_snk, comb, outp, N);
  hipLaunchKernelGGL(k_head1, dim3(gN64), dim3(TB), 0, stream,
                     rsS, colS, rsK, colK, comb, x, W_d1, b_d1, outp, N);
}

// Round 4
// 1168.973 us; speedup vs baseline: 1.5779x; 1.2076x over previous
//
#include <hip/hip_runtime.h>

#define NEG_SLOPE 0.2f
#define PRELU_W 0.1f

__device__ __forceinline__ float d_lrelu(float v){ return fmaxf(v, NEG_SLOPE * v); }
__device__ __forceinline__ float d_prelu(float v){ return fmaxf(v, PRELU_W * v); }

// bf16 helpers (round-to-nearest-even), no header dependency
__device__ __forceinline__ unsigned short f2bf(float f){
  unsigned int u = __builtin_bit_cast(unsigned int, f);
  unsigned int r = (u + 0x7fffu + ((u >> 16) & 1u)) >> 16;
  return (unsigned short)r;
}
__device__ __forceinline__ float bf2f(unsigned short h){
  unsigned int u = ((unsigned int)h) << 16;
  return __builtin_bit_cast(float, u);
}
__device__ __forceinline__ float bflo(unsigned int u){ return __builtin_bit_cast(float, u << 16); }
__device__ __forceinline__ float bfhi(unsigned int u){ return __builtin_bit_cast(float, u & 0xffff0000u); }

// ============================ CSR build ============================

__global__ void k_zero(int* __restrict__ p, int n){
  int i = blockIdx.x * 256 + threadIdx.x;
  if (i < n) p[i] = 0;
}

__global__ void k_count(const int* __restrict__ ei, int* __restrict__ deg, int E){
  int e = blockIdx.x * 256 + threadIdx.x;
  if (e < E) atomicAdd(&deg[ei[E + e]], 1);
}

// chunk=1024 per block (256 thr x 4)
__global__ void k_scan1(const int* __restrict__ deg, int* __restrict__ bsum, int n){
  int b = blockIdx.x, t = threadIdx.x;
  int base = b * 1024 + t * 4;
  int s = 0;
  #pragma unroll
  for (int k2 = 0; k2 < 4; ++k2){ int i = base + k2; if (i < n) s += deg[i]; }
  #pragma unroll
  for (int d = 32; d >= 1; d >>= 1) s += __shfl_xor(s, d, 64);
  __shared__ int ws[4];
  int lane = t & 63, wid = t >> 6;
  if (lane == 0) ws[wid] = s;
  __syncthreads();
  if (t == 0) bsum[b] = ws[0] + ws[1] + ws[2] + ws[3];
}

// single block, 128 threads: exclusive-scan bsum (nb <= 128), write rs[n]=total
__global__ void k_scan2(int* __restrict__ bsum, int nb, int* __restrict__ rs, int n){
  int t = threadIdx.x;
  int v = (t < nb) ? bsum[t] : 0;
  int x = v;
  int lane = t & 63, wid = t >> 6;
  #pragma unroll
  for (int d = 1; d < 64; d <<= 1){ int y = __shfl_up(x, d, 64); if (lane >= d) x += y; }
  __shared__ int wq[2];
  if (lane == 63) wq[wid] = x;
  __syncthreads();
  if (wid == 1) x += wq[0];
  if (t < nb) bsum[t] = x - v;
  if (t == nb - 1) rs[n] = x;
}

__global__ void k_scan3(const int* __restrict__ deg, const int* __restrict__ bsum,
                        int* __restrict__ rs, int n){
  int b = blockIdx.x, t = threadIdx.x;
  int base = b * 1024 + t * 4;
  int v[4];
  #pragma unroll
  for (int k2 = 0; k2 < 4; ++k2){ int i = base + k2; v[k2] = (i < n) ? deg[i] : 0; }
  int tsum = v[0] + v[1] + v[2] + v[3];
  int x = tsum;
  int lane = t & 63, wid = t >> 6;
  #pragma unroll
  for (int d = 1; d < 64; d <<= 1){ int y = __shfl_up(x, d, 64); if (lane >= d) x += y; }
  __shared__ int ws[4];
  if (lane == 63) ws[wid] = x;
  __syncthreads();
  int woff = 0;
  for (int w = 0; w < wid; ++w) woff += ws[w];
  int run = bsum[b] + woff + (x - tsum);
  #pragma unroll
  for (int k2 = 0; k2 < 4; ++k2){ int i = base + k2; if (i < n) rs[i] = run; run += v[k2]; }
}

__global__ void k_copy(const int* __restrict__ a, int* __restrict__ b, int n){
  int i = blockIdx.x * 256 + threadIdx.x;
  if (i < n) b[i] = a[i];
}

__global__ void k_scatter(const int* __restrict__ ei, int* __restrict__ cur,
                          int* __restrict__ col, int E){
  int e = blockIdx.x * 256 + threadIdx.x;
  if (e < E){
    int s = ei[e], d = ei[E + e];
    int p = atomicAdd(&cur[d], 1);
    col[p] = s;
  }
}

// ============================ GAT layer 1 (x is [N,1]) ============================
// h[s] = x[s]*W  => out[d] = (sum_j alpha_j x[s_j]) * W + b.
// Fully per-lane accumulation (scalar softmax invariant in k), fused both graphs.
__global__ void k_gat_l1(const int* __restrict__ rsA, const int* __restrict__ colA,
                         const int* __restrict__ rsB, const int* __restrict__ colB,
                         const float* __restrict__ x,
                         const float* __restrict__ WA, const float* __restrict__ bA,
                         const float* __restrict__ a1A, const float* __restrict__ a2A,
                         const float* __restrict__ WB, const float* __restrict__ bB,
                         const float* __restrict__ a1B, const float* __restrict__ a2B,
                         float* __restrict__ outA, float* __restrict__ outB, int n){
  bool g = (blockIdx.y != 0);
  const int* rs  = g ? rsB  : rsA;
  const int* col = g ? colB : colA;
  const float* W = g ? WB : WA;  const float* bias = g ? bB : bA;
  const float* a1 = g ? a1B : a1A; const float* a2 = g ? a2B : a2A;
  float* outp = g ? outB : outA;

  int gid = blockIdx.x * 256 + threadIdx.x;
  int node = gid >> 5, k = gid & 31;
  if (node >= n) return;
  float Wk = W[k];
  float p1 = Wk * a1[k], p2 = Wk * a2[k];
  #pragma unroll
  for (int d = 16; d >= 1; d >>= 1){ p1 += __shfl_xor(p1, d, 32); p2 += __shfl_xor(p2, d, 32); }
  float a2d = x[node] * p2;
  int beg = rs[node], end = rs[node + 1];
  float denom = 0.f, accx = 0.f;
  #pragma unroll 2
  for (int idx = beg + k; idx < end; idx += 32){
    float xs = x[col[idx]];
    float w = __expf(d_lrelu(xs * p1 + a2d));
    denom += w;
    accx += w * xs;
  }
  #pragma unroll
  for (int d = 16; d >= 1; d >>= 1){
    denom += __shfl_xor(denom, d, 32);
    accx  += __shfl_xor(accx,  d, 32);
  }
  float o = accx / (denom + 1e-16f) * Wk + bias[k];
  outp[node * 32 + k] = d_prelu(o);
}

// ============================ per-layer linear ============================
// c = se+sk ; hS = c@WS ; hK = c@WK (stored bf16); attention dots for both graphs.
__global__ void k_linear(const float* __restrict__ se, const float* __restrict__ sk,
                         const float* __restrict__ WS, const float* __restrict__ WK,
                         const float* __restrict__ a1S, const float* __restrict__ a2S,
                         const float* __restrict__ a1K, const float* __restrict__ a2K,
                         unsigned short* __restrict__ hS, unsigned short* __restrict__ hK,
                         float* __restrict__ oa1S, float* __restrict__ oa2S,
                         float* __restrict__ oa1K, float* __restrict__ oa2K, int n){
  __shared__ float sWS[1024], sWK[1024], sa[128];
  int t = threadIdx.x;
  for (int i = t; i < 1024; i += 256){ sWS[i] = WS[i]; sWK[i] = WK[i]; }
  if (t < 32){ sa[t] = a1S[t]; sa[32 + t] = a2S[t]; sa[64 + t] = a1K[t]; sa[96 + t] = a2K[t]; }
  __syncthreads();
  int gid = blockIdx.x * 256 + t;
  int node = gid >> 5, k = gid & 31;
  if (node >= n) return;
  float c = se[node * 32 + k] + sk[node * 32 + k];
  float hs = 0.f, hk = 0.f;
  #pragma unroll
  for (int m = 0; m < 32; ++m){
    float cm = __shfl(c, m, 32);
    hs += cm * sWS[m * 32 + k];
    hk += cm * sWK[m * 32 + k];
  }
  hS[node * 32 + k] = f2bf(hs);
  hK[node * 32 + k] = f2bf(hk);
  float r1 = hs * sa[k], r2 = hs * sa[32 + k], r3 = hk * sa[64 + k], r4 = hk * sa[96 + k];
  #pragma unroll
  for (int d = 16; d >= 1; d >>= 1){
    r1 += __shfl_xor(r1, d, 32); r2 += __shfl_xor(r2, d, 32);
    r3 += __shfl_xor(r3, d, 32); r4 += __shfl_xor(r4, d, 32);
  }
  if (k == 0){ oa1S[node] = r1; oa2S[node] = r2; oa1K[node] = r3; oa2K[node] = r4; }
}

// ============================ generic GAT aggregation (k-sliced) ============================
// One 64-lane wave per dst node: 8 edge-groups x 8 k-lanes (k-slice of 4 via uint2).
// All lanes in a group load the SAME col/a1 address (HW broadcast, no shfl);
// weight computed redundantly per lane; butterfly-reduce across groups at the end.
__global__ void k_gat_agg(const int* __restrict__ rsA, const int* __restrict__ colA,
                          const unsigned short* __restrict__ hA,
                          const float* __restrict__ a1A, const float* __restrict__ a2A,
                          const float* __restrict__ bA, float* __restrict__ outA,
                          const int* __restrict__ rsB, const int* __restrict__ colB,
                          const unsigned short* __restrict__ hB,
                          const float* __restrict__ a1B, const float* __restrict__ a2B,
                          const float* __restrict__ bB, float* __restrict__ outB, int n){
  bool g = (blockIdx.y != 0);
  const int* rs  = g ? rsB  : rsA;
  const int* col = g ? colB : colA;
  const unsigned short* h = g ? hB : hA;
  const float* a1 = g ? a1B : a1A;
  const float* a2 = g ? a2B : a2A;
  const float* bias = g ? bB : bA;
  float* outp = g ? outB : outA;

  int lane = threadIdx.x & 63;
  int node = blockIdx.x * 4 + (threadIdx.x >> 6);
  if (node >= n) return;
  int e3 = lane >> 3, k = (lane & 7) * 4;
  float a2d = a2[node];
  int beg = rs[node], end = rs[node + 1];
  float acc0 = 0.f, acc1 = 0.f, acc2 = 0.f, acc3 = 0.f, dpart = 0.f;
  #pragma unroll 2
  for (int idx = beg + e3; idx < end; idx += 8){
    int s = col[idx];
    float w = __expf(d_lrelu(a1[s] + a2d));
    uint2 hv = *(const uint2*)(h + (((size_t)s) << 5) + k);
    dpart += w;
    acc0 += w * bflo(hv.x);
    acc1 += w * bfhi(hv.x);
    acc2 += w * bflo(hv.y);
    acc3 += w * bfhi(hv.y);
  }
  #pragma unroll
  for (int m = 8; m <= 32; m <<= 1){
    acc0 += __shfl_xor(acc0, m, 64);
    acc1 += __shfl_xor(acc1, m, 64);
    acc2 += __shfl_xor(acc2, m, 64);
    acc3 += __shfl_xor(acc3, m, 64);
    dpart += __shfl_xor(dpart, m, 64);
  }
  if (e3 == 0){
    float inv = 1.f / (dpart + 1e-16f);
    float4 o;
    o.x = d_prelu(acc0 * inv + bias[k + 0]);
    o.y = d_prelu(acc1 * inv + bias[k + 1]);
    o.z = d_prelu(acc2 * inv + bias[k + 2]);
    o.w = d_prelu(acc3 * inv + bias[k + 3]);
    *(float4*)(outp + (size_t)node * 32 + k) = o;
  }
}

// ============================ output head 0 ============================
// comb = [se|sk] stored bf16; final_dim0 = (relu(comb@Wos+bos)+relu(comb@Wok+bok))/2
__global__ void k_head0(const float* __restrict__ se, const float* __restrict__ sk,
                        const float* __restrict__ Wos, const float* __restrict__ bos,
                        const float* __restrict__ Wok, const float* __restrict__ bok,
                        unsigned short* __restrict__ comb, float* __restrict__ outp, int n){
  int gid = blockIdx.x * 256 + threadIdx.x;
  int node = gid >> 6, k = gid & 63;
  if (node >= n) return;
  float cv = (k < 32) ? se[node * 32 + k] : sk[node * 32 + (k - 32)];
  comb[(size_t)node * 64 + k] = f2bf(cv);
  float s0 = cv * Wos[k * 2], s1 = cv * Wos[k * 2 + 1];
  float q0 = cv * Wok[k * 2], q1 = cv * Wok[k * 2 + 1];
  #pragma unroll
  for (int d = 32; d >= 1; d >>= 1){
    s0 += __shfl_xor(s0, d, 64); s1 += __shfl_xor(s1, d, 64);
    q0 += __shfl_xor(q0, d, 64); q1 += __shfl_xor(q1, d, 64);
  }
  if (k == 0){
    float f0 = (fmaxf(s0 + bos[0], 0.f) + fmaxf(q0 + bok[0], 0.f)) * 0.5f;
    float f1 = (fmaxf(s1 + bos[1], 0.f) + fmaxf(q1 + bok[1], 0.f)) * 0.5f;
    outp[node * 4 + 0] = f0;
    outp[node * 4 + 1] = f1;
  }
}

// ============================ output head 1 (edge_neighbor, k-sliced) ============================
// One 64-lane wave per node: 4 edge-groups x 16 k-lanes (k-slice of 4 via uint2).
// col/x loads are group-uniform (HW broadcast); comb slice per lane; no shfl in loop.
__global__ void k_head1(const int* __restrict__ rsS, const int* __restrict__ colS,
                        const int* __restrict__ rsK, const int* __restrict__ colK,
                        const unsigned short* __restrict__ comb, const float* __restrict__ x,
                        const float* __restrict__ Wd1, const float* __restrict__ bd1,
                        float* __restrict__ outp, int n){
  int lane = threadIdx.x & 63;
  int node = blockIdx.x * 4 + (threadIdx.x >> 6);
  if (node >= n) return;
  int e2 = lane >> 4, k = (lane & 15) * 4;
  float s0=0.f,s1=0.f,s2=0.f,s3=0.f, q0=0.f,q1=0.f,q2=0.f,q3=0.f;
  {
    int beg = rsS[node], end = rsS[node + 1];
    #pragma unroll 2
    for (int idx = beg + e2; idx < end; idx += 4){
      int s = colS[idx];
      float xs = x[s];
      uint2 cv = *(const uint2*)(comb + (((size_t)s) << 6) + k);
      s0 += xs * bflo(cv.x); s1 += xs * bfhi(cv.x);
      s2 += xs * bflo(cv.y); s3 += xs * bfhi(cv.y);
    }
  }
  {
    int beg = rsK[node], end = rsK[node + 1];
    #pragma unroll 2
    for (int idx = beg + e2; idx < end; idx += 4){
      int s = colK[idx];
      float xs = x[s];
      uint2 cv = *(const uint2*)(comb + (((size_t)s) << 6) + k);
      q0 += xs * bflo(cv.x); q1 += xs * bfhi(cv.x);
      q2 += xs * bflo(cv.y); q3 += xs * bfhi(cv.y);
    }
  }
  #pragma unroll
  for (int m = 16; m <= 32; m <<= 1){
    s0 += __shfl_xor(s0, m, 64); s1 += __shfl_xor(s1, m, 64);
    s2 += __shfl_xor(s2, m, 64); s3 += __shfl_xor(s3, m, 64);
    q0 += __shfl_xor(q0, m, 64); q1 += __shfl_xor(q1, m, 64);
    q2 += __shfl_xor(q2, m, 64); q3 += __shfl_xor(q3, m, 64);
  }
  uint2 cself = *(const uint2*)(comb + (((size_t)node) << 6) + k);
  float c0 = bflo(cself.x)*0.5f, c1 = bfhi(cself.x)*0.5f;
  float c2 = bflo(cself.y)*0.5f, c3 = bfhi(cself.y)*0.5f;
  float t0 = fmaxf(s0 + c0, 0.f) + fmaxf(q0 + c0, 0.f);
  float t1 = fmaxf(s1 + c1, 0.f) + fmaxf(q1 + c1, 0.f);
  float t2 = fmaxf(s2 + c2, 0.f) + fmaxf(q2 + c2, 0.f);
  float t3 = fmaxf(s3 + c3, 0.f) + fmaxf(q3 + c3, 0.f);
  float2 w0 = *(const float2*)(Wd1 + (k + 0) * 2);
  float2 w1 = *(const float2*)(Wd1 + (k + 1) * 2);
  float2 w2 = *(const float2*)(Wd1 + (k + 2) * 2);
  float2 w3 = *(const float2*)(Wd1 + (k + 3) * 2);
  float r0 = t0 * w0.x + t1 * w1.x + t2 * w2.x + t3 * w3.x;
  float r1 = t0 * w0.y + t1 * w1.y + t2 * w2.y + t3 * w3.y;
  #pragma unroll
  for (int m = 1; m <= 8; m <<= 1){
    r0 += __shfl_xor(r0, m, 64); r1 += __shfl_xor(r1, m, 64);
  }
  if (lane == 0){
    outp[(size_t)node * 4 + 2] = fmaxf(r0 + bd1[0], 0.f);
    outp[(size_t)node * 4 + 3] = fmaxf(r1 + bd1[1], 0.f);
  }
}

// ============================ launch ============================

extern "C" void kernel_launch(void* const* d_in, const int* in_sizes, int n_in,
                              void* d_out, int out_size, void* d_ws, size_t ws_size,
                              hipStream_t stream) {
  const float* x      = (const float*)d_in[0];
  const int*   eiS    = (const int*)d_in[1];
  const int*   eiK    = (const int*)d_in[2];
  const float* W_in_src = (const float*)d_in[3];
  const float* b_in_src = (const float*)d_in[4];
  const float* a1_in_src= (const float*)d_in[5];
  const float* a2_in_src= (const float*)d_in[6];
  const float* W_in_snk = (const float*)d_in[7];
  const float* b_in_snk = (const float*)d_in[8];
  const float* a1_in_snk= (const float*)d_in[9];
  const float* a2_in_snk= (const float*)d_in[10];
  const float* W_src  = (const float*)d_in[11];
  const float* b_src  = (const float*)d_in[12];
  const float* a1_src = (const float*)d_in[13];
  const float* a2_src = (const float*)d_in[14];
  const float* W_snk  = (const float*)d_in[15];
  const float* b_snk  = (const float*)d_in[16];
  const float* a1_snk = (const float*)d_in[17];
  const float* a2_snk = (const float*)d_in[18];
  const float* W_o_src= (const float*)d_in[19];
  const float* b_o_src= (const float*)d_in[20];
  const float* W_o_snk= (const float*)d_in[21];
  const float* b_o_snk= (const float*)d_in[22];
  const float* W_d1   = (const float*)d_in[23];
  const float* b_d1   = (const float*)d_in[24];
  float* outp = (float*)d_out;

  const int N = in_sizes[0];       // 100000
  const int E = in_sizes[1] / 2;   // 1600000
  const int L = 5;

  // ---- workspace layout: floats, then ints, then ushorts ----
  float* f = (float*)d_ws;
  float* seA = f;  f += (size_t)N * 32;
  float* skA = f;  f += (size_t)N * 32;
  float* a1Sv = f; f += N;
  float* a2Sv = f; f += N;
  float* a1Kv = f; f += N;
  float* a2Kv = f; f += N;
  int* ip = (int*)f;
  int* rsS    = ip; ip += N + 1;
  int* rsK    = ip; ip += N + 1;
  int* colS   = ip; ip += E;
  int* colK   = ip; ip += E;
  int* cursor = ip; ip += N;
  int* bsum   = ip; ip += 256;
  unsigned short* us = (unsigned short*)ip;
  unsigned short* hS   = us; us += (size_t)N * 32;
  unsigned short* hK   = us; us += (size_t)N * 32;
  unsigned short* comb = us; us += (size_t)N * 64;

  const int TB = 256;
  int gN    = (N + TB - 1) / TB;
  int gE    = (E + TB - 1) / TB;
  int gN32  = (N * 32 + TB - 1) / TB;
  int gN64  = (N * 64 + TB - 1) / TB;
  int gNode4 = (N + 3) / 4;
  int nb    = (N + 1023) / 1024;

  // ---- CSR build: source graph ----
  hipLaunchKernelGGL(k_zero,   dim3(gN), dim3(TB), 0, stream, cursor, N);
  hipLaunchKernelGGL(k_count,  dim3(gE), dim3(TB), 0, stream, eiS, cursor, E);
  hipLaunchKernelGGL(k_scan1,  dim3(nb), dim3(TB), 0, stream, cursor, bsum, N);
  hipLaunchKernelGGL(k_scan2,  dim3(1),  dim3(128), 0, stream, bsum, nb, rsS, N);
  hipLaunchKernelGGL(k_scan3,  dim3(nb), dim3(TB), 0, stream, cursor, bsum, rsS, N);
  hipLaunchKernelGGL(k_copy,   dim3(gN), dim3(TB), 0, stream, rsS, cursor, N);
  hipLaunchKernelGGL(k_scatter,dim3(gE), dim3(TB), 0, stream, eiS, cursor, colS, E);
  // ---- CSR build: sink graph ----
  hipLaunchKernelGGL(k_zero,   dim3(gN), dim3(TB), 0, stream, cursor, N);
  hipLaunchKernelGGL(k_count,  dim3(gE), dim3(TB), 0, stream, eiK, cursor, E);
  hipLaunchKernelGGL(k_scan1,  dim3(nb), dim3(TB), 0, stream, cursor, bsum, N);
  hipLaunchKernelGGL(k_scan2,  dim3(1),  dim3(128), 0, stream, bsum, nb, rsK, N);
  hipLaunchKernelGGL(k_scan3,  dim3(nb), dim3(TB), 0, stream, cursor, bsum, rsK, N);
  hipLaunchKernelGGL(k_copy,   dim3(gN), dim3(TB), 0, stream, rsK, cursor, N);
  hipLaunchKernelGGL(k_scatter,dim3(gE), dim3(TB), 0, stream, eiK, cursor, colK, E);

  // ---- layer 1 (input), both graphs fused via grid.y ----
  hipLaunchKernelGGL(k_gat_l1, dim3(gN32, 2), dim3(TB), 0, stream,
                     rsS, colS, rsK, colK, x,
                     W_in_src, b_in_src, a1_in_src, a2_in_src,
                     W_in_snk, b_in_snk, a1_in_snk, a2_in_snk,
                     seA, skA, N);

  // ---- layers 2..L ----
  for (int i = 0; i < L - 1; ++i){
    hipLaunchKernelGGL(k_linear, dim3(gN32), dim3(TB), 0, stream,
                       seA, skA, W_src + (size_t)i * 1024, W_snk + (size_t)i * 1024,
                       a1_src + i * 32, a2_src + i * 32, a1_snk + i * 32, a2_snk + i * 32,
                       hS, hK, a1Sv, a2Sv, a1Kv, a2Kv, N);
    hipLaunchKernelGGL(k_gat_agg, dim3(gNode4, 2), dim3(TB), 0, stream,
                       rsS, colS, hS, a1Sv, a2Sv, b_src + i * 32, seA,
                       rsK, colK, hK, a1Kv, a2Kv, b_snk + i * 32, skA, N);
  }

  // ---- heads ----
  hipLaunchKernelGGL(k_head0, dim3(gN64), dim3(TB), 0, stream,
                     seA, skA, W_o_src, b_o_src, W_o_snk, b_o_snk, comb, outp, N);
  hipLaunchKernelGGL(k_head1, dim3(gNode4), dim3(TB), 0, stream,
                     rsS, colS, rsK, colK, comb, x, W_d1, b_d1, outp, N);
}

// Round 5
// 935.667 us; speedup vs baseline: 1.9713x; 1.2493x over previous
//
#include <hip/hip_runtime.h>

#define NEG_SLOPE 0.2f
#define PRELU_W 0.1f

__device__ __forceinline__ float d_lrelu(float v){ return fmaxf(v, NEG_SLOPE * v); }
__device__ __forceinline__ float d_prelu(float v){ return fmaxf(v, PRELU_W * v); }

// bf16 helpers (round-to-nearest-even), no header dependency
__device__ __forceinline__ unsigned short f2bf(float f){
  unsigned int u = __builtin_bit_cast(unsigned int, f);
  unsigned int r = (u + 0x7fffu + ((u >> 16) & 1u)) >> 16;
  return (unsigned short)r;
}
__device__ __forceinline__ float bf2f(unsigned short h){
  unsigned int u = ((unsigned int)h) << 16;
  return __builtin_bit_cast(float, u);
}
__device__ __forceinline__ float bflo(unsigned int u){ return __builtin_bit_cast(float, u << 16); }
__device__ __forceinline__ float bfhi(unsigned int u){ return __builtin_bit_cast(float, u & 0xffff0000u); }

// ============================ CSR build ============================

__global__ void k_zero(int* __restrict__ p, int n){
  int i = blockIdx.x * 256 + threadIdx.x;
  if (i < n) p[i] = 0;
}

// Count degrees for BOTH graphs; atomicAdd's return value IS the edge's rank
// within its destination -> stored coalesced, kills the scatter's atomic chain.
__global__ void k_count_rank(const int* __restrict__ eiS, const int* __restrict__ eiK,
                             int* __restrict__ degS, int* __restrict__ degK,
                             int* __restrict__ rankS, int* __restrict__ rankK, int E){
  int e = blockIdx.x * 256 + threadIdx.x;
  if (e < E){
    int dS = eiS[E + e];
    int dK = eiK[E + e];
    rankS[e] = atomicAdd(&degS[dS], 1);
    rankK[e] = atomicAdd(&degK[dK], 1);
  }
}

// chunk=1024 per block (256 thr x 4); grid.y selects graph
__global__ void k_scan1(const int* __restrict__ degS, const int* __restrict__ degK,
                        int* __restrict__ bsumS, int* __restrict__ bsumK, int n){
  const int* deg = blockIdx.y ? degK : degS;
  int* bsum = blockIdx.y ? bsumK : bsumS;
  int b = blockIdx.x, t = threadIdx.x;
  int base = b * 1024 + t * 4;
  int s = 0;
  #pragma unroll
  for (int k2 = 0; k2 < 4; ++k2){ int i = base + k2; if (i < n) s += deg[i]; }
  #pragma unroll
  for (int d = 32; d >= 1; d >>= 1) s += __shfl_xor(s, d, 64);
  __shared__ int ws[4];
  int lane = t & 63, wid = t >> 6;
  if (lane == 0) ws[wid] = s;
  __syncthreads();
  if (t == 0) bsum[b] = ws[0] + ws[1] + ws[2] + ws[3];
}

// 2 blocks (one per graph), 128 threads: exclusive-scan bsum (nb <= 128)
__global__ void k_scan2(int* __restrict__ bsumS, int* __restrict__ bsumK, int nb,
                        int* __restrict__ rsS, int* __restrict__ rsK, int n){
  int* bsum = blockIdx.x ? bsumK : bsumS;
  int* rs = blockIdx.x ? rsK : rsS;
  int t = threadIdx.x;
  int v = (t < nb) ? bsum[t] : 0;
  int x = v;
  int lane = t & 63, wid = t >> 6;
  #pragma unroll
  for (int d = 1; d < 64; d <<= 1){ int y = __shfl_up(x, d, 64); if (lane >= d) x += y; }
  __shared__ int wq[2];
  if (lane == 63) wq[wid] = x;
  __syncthreads();
  if (wid == 1) x += wq[0];
  if (t < nb) bsum[t] = x - v;
  if (t == nb - 1) rs[n] = x;
}

__global__ void k_scan3(const int* __restrict__ degS, const int* __restrict__ degK,
                        const int* __restrict__ bsumS, const int* __restrict__ bsumK,
                        int* __restrict__ rsS, int* __restrict__ rsK, int n){
  const int* deg = blockIdx.y ? degK : degS;
  const int* bsum = blockIdx.y ? bsumK : bsumS;
  int* rs = blockIdx.y ? rsK : rsS;
  int b = blockIdx.x, t = threadIdx.x;
  int base = b * 1024 + t * 4;
  int v[4];
  #pragma unroll
  for (int k2 = 0; k2 < 4; ++k2){ int i = base + k2; v[k2] = (i < n) ? deg[i] : 0; }
  int tsum = v[0] + v[1] + v[2] + v[3];
  int x = tsum;
  int lane = t & 63, wid = t >> 6;
  #pragma unroll
  for (int d = 1; d < 64; d <<= 1){ int y = __shfl_up(x, d, 64); if (lane >= d) x += y; }
  __shared__ int ws[4];
  if (lane == 63) ws[wid] = x;
  __syncthreads();
  int woff = 0;
  for (int w = 0; w < wid; ++w) woff += ws[w];
  int run = bsum[b] + woff + (x - tsum);
  #pragma unroll
  for (int k2 = 0; k2 < 4; ++k2){ int i = base + k2; if (i < n) rs[i] = run; run += v[k2]; }
}

// Atomic-free placement: slot is rs[d] + precomputed rank. Both graphs fused.
__global__ void k_place(const int* __restrict__ eiS, const int* __restrict__ eiK,
                        const int* __restrict__ rsS, const int* __restrict__ rsK,
                        const int* __restrict__ rankS, const int* __restrict__ rankK,
                        int* __restrict__ colS, int* __restrict__ colK, int E){
  int e = blockIdx.x * 256 + threadIdx.x;
  if (e < E){
    int sS = eiS[e], dS = eiS[E + e];
    int sK = eiK[e], dK = eiK[E + e];
    colS[rsS[dS] + rankS[e]] = sS;
    colK[rsK[dK] + rankK[e]] = sK;
  }
}

// ============================ GAT layer 1 (x is [N,1]) ============================
// 8 lanes per node; p1/p2 (kernel-wide constants) computed once per block in LDS;
// float4 output writes. Both graphs fused via grid.y.
__global__ void k_gat_l1(const int* __restrict__ rsA, const int* __restrict__ colA,
                         const int* __restrict__ rsB, const int* __restrict__ colB,
                         const float* __restrict__ x,
                         const float* __restrict__ WA, const float* __restrict__ bA,
                         const float* __restrict__ a1A, const float* __restrict__ a2A,
                         const float* __restrict__ WB, const float* __restrict__ bB,
                         const float* __restrict__ a1B, const float* __restrict__ a2B,
                         float* __restrict__ outA, float* __restrict__ outB, int n){
  bool g = (blockIdx.y != 0);
  const int* rs  = g ? rsB  : rsA;
  const int* col = g ? colB : colA;
  const float* W = g ? WB : WA;  const float* bias = g ? bB : bA;
  const float* a1 = g ? a1B : a1A; const float* a2 = g ? a2B : a2A;
  float* outp = g ? outB : outA;

  __shared__ float sp[2];
  int t = threadIdx.x;
  if (t < 32){
    float wk = W[t];
    float q1 = wk * a1[t], q2 = wk * a2[t];
    #pragma unroll
    for (int d = 16; d >= 1; d >>= 1){ q1 += __shfl_xor(q1, d, 32); q2 += __shfl_xor(q2, d, 32); }
    if (t == 0){ sp[0] = q1; sp[1] = q2; }
  }
  __syncthreads();
  float p1 = sp[0], p2 = sp[1];

  int gid = blockIdx.x * 256 + t;
  int node = gid >> 3, l8 = gid & 7;
  if (node >= n) return;
  float a2d = x[node] * p2;
  int beg = rs[node], end = rs[node + 1];
  float denom = 0.f, accx = 0.f;
  #pragma unroll 2
  for (int idx = beg + l8; idx < end; idx += 8){
    float xs = x[col[idx]];
    float w = __expf(d_lrelu(xs * p1 + a2d));
    denom += w;
    accx += w * xs;
  }
  #pragma unroll
  for (int d = 4; d >= 1; d >>= 1){
    denom += __shfl_xor(denom, d, 8);
    accx  += __shfl_xor(accx,  d, 8);
  }
  float r = accx / (denom + 1e-16f);
  float4 Wv = *(const float4*)(W + l8 * 4);
  float4 Bv = *(const float4*)(bias + l8 * 4);
  float4 o;
  o.x = d_prelu(r * Wv.x + Bv.x);
  o.y = d_prelu(r * Wv.y + Bv.y);
  o.z = d_prelu(r * Wv.z + Bv.z);
  o.w = d_prelu(r * Wv.w + Bv.w);
  *(float4*)(outp + (size_t)node * 32 + l8 * 4) = o;
}

// ============================ per-layer linear ============================
// c = se+sk ; hS = c@WS ; hK = c@WK (stored bf16); attention dots for both graphs.
__global__ void k_linear(const float* __restrict__ se, const float* __restrict__ sk,
                         const float* __restrict__ WS, const float* __restrict__ WK,
                         const float* __restrict__ a1S, const float* __restrict__ a2S,
                         const float* __restrict__ a1K, const float* __restrict__ a2K,
                         unsigned short* __restrict__ hS, unsigned short* __restrict__ hK,
                         float* __restrict__ oa1S, float* __restrict__ oa2S,
                         float* __restrict__ oa1K, float* __restrict__ oa2K, int n){
  __shared__ float sWS[1024], sWK[1024], sa[128];
  int t = threadIdx.x;
  for (int i = t; i < 1024; i += 256){ sWS[i] = WS[i]; sWK[i] = WK[i]; }
  if (t < 32){ sa[t] = a1S[t]; sa[32 + t] = a2S[t]; sa[64 + t] = a1K[t]; sa[96 + t] = a2K[t]; }
  __syncthreads();
  int gid = blockIdx.x * 256 + t;
  int node = gid >> 5, k = gid & 31;
  if (node >= n) return;
  float c = se[node * 32 + k] + sk[node * 32 + k];
  float hs = 0.f, hk = 0.f;
  #pragma unroll
  for (int m = 0; m < 32; ++m){
    float cm = __shfl(c, m, 32);
    hs += cm * sWS[m * 32 + k];
    hk += cm * sWK[m * 32 + k];
  }
  hS[node * 32 + k] = f2bf(hs);
  hK[node * 32 + k] = f2bf(hk);
  float r1 = hs * sa[k], r2 = hs * sa[32 + k], r3 = hk * sa[64 + k], r4 = hk * sa[96 + k];
  #pragma unroll
  for (int d = 16; d >= 1; d >>= 1){
    r1 += __shfl_xor(r1, d, 32); r2 += __shfl_xor(r2, d, 32);
    r3 += __shfl_xor(r3, d, 32); r4 += __shfl_xor(r4, d, 32);
  }
  if (k == 0){ oa1S[node] = r1; oa2S[node] = r2; oa1K[node] = r3; oa2K[node] = r4; }
}

// ============================ generic GAT aggregation (k-sliced) ============================
// One 64-lane wave per dst node: 8 edge-groups x 8 k-lanes (k-slice of 4 via uint2).
__global__ void k_gat_agg(const int* __restrict__ rsA, const int* __restrict__ colA,
                          const unsigned short* __restrict__ hA,
                          const float* __restrict__ a1A, const float* __restrict__ a2A,
                          const float* __restrict__ bA, float* __restrict__ outA,
                          const int* __restrict__ rsB, const int* __restrict__ colB,
                          const unsigned short* __restrict__ hB,
                          const float* __restrict__ a1B, const float* __restrict__ a2B,
                          const float* __restrict__ bB, float* __restrict__ outB, int n){
  bool g = (blockIdx.y != 0);
  const int* rs  = g ? rsB  : rsA;
  const int* col = g ? colB : colA;
  const unsigned short* h = g ? hB : hA;
  const float* a1 = g ? a1B : a1A;
  const float* a2 = g ? a2B : a2A;
  const float* bias = g ? bB : bA;
  float* outp = g ? outB : outA;

  int lane = threadIdx.x & 63;
  int node = blockIdx.x * 4 + (threadIdx.x >> 6);
  if (node >= n) return;
  int e3 = lane >> 3, k = (lane & 7) * 4;
  float a2d = a2[node];
  int beg = rs[node], end = rs[node + 1];
  float acc0 = 0.f, acc1 = 0.f, acc2 = 0.f, acc3 = 0.f, dpart = 0.f;
  #pragma unroll 2
  for (int idx = beg + e3; idx < end; idx += 8){
    int s = col[idx];
    float w = __expf(d_lrelu(a1[s] + a2d));
    uint2 hv = *(const uint2*)(h + (((size_t)s) << 5) + k);
    dpart += w;
    acc0 += w * bflo(hv.x);
    acc1 += w * bfhi(hv.x);
    acc2 += w * bflo(hv.y);
    acc3 += w * bfhi(hv.y);
  }
  #pragma unroll
  for (int m = 8; m <= 32; m <<= 1){
    acc0 += __shfl_xor(acc0, m, 64);
    acc1 += __shfl_xor(acc1, m, 64);
    acc2 += __shfl_xor(acc2, m, 64);
    acc3 += __shfl_xor(acc3, m, 64);
    dpart += __shfl_xor(dpart, m, 64);
  }
  if (e3 == 0){
    float inv = 1.f / (dpart + 1e-16f);
    float4 bv = *(const float4*)(bias + k);
    float4 o;
    o.x = d_prelu(acc0 * inv + bv.x);
    o.y = d_prelu(acc1 * inv + bv.y);
    o.z = d_prelu(acc2 * inv + bv.z);
    o.w = d_prelu(acc3 * inv + bv.w);
    *(float4*)(outp + (size_t)node * 32 + k) = o;
  }
}

// ============================ output head 0 ============================
__global__ void k_head0(const float* __restrict__ se, const float* __restrict__ sk,
                        const float* __restrict__ Wos, const float* __restrict__ bos,
                        const float* __restrict__ Wok, const float* __restrict__ bok,
                        unsigned short* __restrict__ comb, float* __restrict__ outp, int n){
  int gid = blockIdx.x * 256 + threadIdx.x;
  int node = gid >> 6, k = gid & 63;
  if (node >= n) return;
  float cv = (k < 32) ? se[node * 32 + k] : sk[node * 32 + (k - 32)];
  comb[(size_t)node * 64 + k] = f2bf(cv);
  float s0 = cv * Wos[k * 2], s1 = cv * Wos[k * 2 + 1];
  float q0 = cv * Wok[k * 2], q1 = cv * Wok[k * 2 + 1];
  #pragma unroll
  for (int d = 32; d >= 1; d >>= 1){
    s0 += __shfl_xor(s0, d, 64); s1 += __shfl_xor(s1, d, 64);
    q0 += __shfl_xor(q0, d, 64); q1 += __shfl_xor(q1, d, 64);
  }
  if (k == 0){
    float f0 = (fmaxf(s0 + bos[0], 0.f) + fmaxf(q0 + bok[0], 0.f)) * 0.5f;
    float f1 = (fmaxf(s1 + bos[1], 0.f) + fmaxf(q1 + bok[1], 0.f)) * 0.5f;
    outp[node * 4 + 0] = f0;
    outp[node * 4 + 1] = f1;
  }
}

// ============================ output head 1 (edge_neighbor, k-sliced) ============================
__global__ void k_head1(const int* __restrict__ rsS, const int* __restrict__ colS,
                        const int* __restrict__ rsK, const int* __restrict__ colK,
                        const unsigned short* __restrict__ comb, const float* __restrict__ x,
                        const float* __restrict__ Wd1, const float* __restrict__ bd1,
                        float* __restrict__ outp, int n){
  int lane = threadIdx.x & 63;
  int node = blockIdx.x * 4 + (threadIdx.x >> 6);
  if (node >= n) return;
  int e2 = lane >> 4, k = (lane & 15) * 4;
  float s0=0.f,s1=0.f,s2=0.f,s3=0.f, q0=0.f,q1=0.f,q2=0.f,q3=0.f;
  {
    int beg = rsS[node], end = rsS[node + 1];
    #pragma unroll 2
    for (int idx = beg + e2; idx < end; idx += 4){
      int s = colS[idx];
      float xs = x[s];
      uint2 cv = *(const uint2*)(comb + (((size_t)s) << 6) + k);
      s0 += xs * bflo(cv.x); s1 += xs * bfhi(cv.x);
      s2 += xs * bflo(cv.y); s3 += xs * bfhi(cv.y);
    }
  }
  {
    int beg = rsK[node], end = rsK[node + 1];
    #pragma unroll 2
    for (int idx = beg + e2; idx < end; idx += 4){
      int s = colK[idx];
      float xs = x[s];
      uint2 cv = *(const uint2*)(comb + (((size_t)s) << 6) + k);
      q0 += xs * bflo(cv.x); q1 += xs * bfhi(cv.x);
      q2 += xs * bflo(cv.y); q3 += xs * bfhi(cv.y);
    }
  }
  #pragma unroll
  for (int m = 16; m <= 32; m <<= 1){
    s0 += __shfl_xor(s0, m, 64); s1 += __shfl_xor(s1, m, 64);
    s2 += __shfl_xor(s2, m, 64); s3 += __shfl_xor(s3, m, 64);
    q0 += __shfl_xor(q0, m, 64); q1 += __shfl_xor(q1, m, 64);
    q2 += __shfl_xor(q2, m, 64); q3 += __shfl_xor(q3, m, 64);
  }
  uint2 cself = *(const uint2*)(comb + (((size_t)node) << 6) + k);
  float c0 = bflo(cself.x)*0.5f, c1 = bfhi(cself.x)*0.5f;
  float c2 = bflo(cself.y)*0.5f, c3 = bfhi(cself.y)*0.5f;
  float t0 = fmaxf(s0 + c0, 0.f) + fmaxf(q0 + c0, 0.f);
  float t1 = fmaxf(s1 + c1, 0.f) + fmaxf(q1 + c1, 0.f);
  float t2 = fmaxf(s2 + c2, 0.f) + fmaxf(q2 + c2, 0.f);
  float t3 = fmaxf(s3 + c3, 0.f) + fmaxf(q3 + c3, 0.f);
  float2 w0 = *(const float2*)(Wd1 + (k + 0) * 2);
  float2 w1 = *(const float2*)(Wd1 + (k + 1) * 2);
  float2 w2 = *(const float2*)(Wd1 + (k + 2) * 2);
  float2 w3 = *(const float2*)(Wd1 + (k + 3) * 2);
  float r0 = t0 * w0.x + t1 * w1.x + t2 * w2.x + t3 * w3.x;
  float r1 = t0 * w0.y + t1 * w1.y + t2 * w2.y + t3 * w3.y;
  #pragma unroll
  for (int m = 1; m <= 8; m <<= 1){
    r0 += __shfl_xor(r0, m, 64); r1 += __shfl_xor(r1, m, 64);
  }
  if (lane == 0){
    outp[(size_t)node * 4 + 2] = fmaxf(r0 + bd1[0], 0.f);
    outp[(size_t)node * 4 + 3] = fmaxf(r1 + bd1[1], 0.f);
  }
}

// ============================ launch ============================

extern "C" void kernel_launch(void* const* d_in, const int* in_sizes, int n_in,
                              void* d_out, int out_size, void* d_ws, size_t ws_size,
                              hipStream_t stream) {
  const float* x      = (const float*)d_in[0];
  const int*   eiS    = (const int*)d_in[1];
  const int*   eiK    = (const int*)d_in[2];
  const float* W_in_src = (const float*)d_in[3];
  const float* b_in_src = (const float*)d_in[4];
  const float* a1_in_src= (const float*)d_in[5];
  const float* a2_in_src= (const float*)d_in[6];
  const float* W_in_snk = (const float*)d_in[7];
  const float* b_in_snk = (const float*)d_in[8];
  const float* a1_in_snk= (const float*)d_in[9];
  const float* a2_in_snk= (const float*)d_in[10];
  const float* W_src  = (const float*)d_in[11];
  const float* b_src  = (const float*)d_in[12];
  const float* a1_src = (const float*)d_in[13];
  const float* a2_src = (const float*)d_in[14];
  const float* W_snk  = (const float*)d_in[15];
  const float* b_snk  = (const float*)d_in[16];
  const float* a1_snk = (const float*)d_in[17];
  const float* a2_snk = (const float*)d_in[18];
  const float* W_o_src= (const float*)d_in[19];
  const float* b_o_src= (const float*)d_in[20];
  const float* W_o_snk= (const float*)d_in[21];
  const float* b_o_snk= (const float*)d_in[22];
  const float* W_d1   = (const float*)d_in[23];
  const float* b_d1   = (const float*)d_in[24];
  float* outp = (float*)d_out;

  const int N = in_sizes[0];       // 100000
  const int E = in_sizes[1] / 2;   // 1600000
  const int L = 5;

  // ---- workspace layout: floats, then ints, then ushorts ----
  float* f = (float*)d_ws;
  float* seA = f;  f += (size_t)N * 32;
  float* skA = f;  f += (size_t)N * 32;
  float* a1Sv = f; f += N;
  float* a2Sv = f; f += N;
  float* a1Kv = f; f += N;
  float* a2Kv = f; f += N;
  int* ip = (int*)f;
  int* rsS    = ip; ip += N + 1;
  int* rsK    = ip; ip += N + 1;
  int* colS   = ip; ip += E;
  int* colK   = ip; ip += E;
  int* degS   = ip; ip += N;   // degS/degK adjacent -> single zero pass
  int* degK   = ip; ip += N;
  int* bsumS  = ip; ip += 256;
  int* bsumK  = ip; ip += 256;
  unsigned short* us = (unsigned short*)ip;
  unsigned short* hS   = us; us += (size_t)N * 32;
  unsigned short* hK   = us; us += (size_t)N * 32;
  unsigned short* comb = us; us += (size_t)N * 64;
  // rank arrays alias hS/hK: dead before k_linear first writes them (E ints == N*32 ushorts)
  int* rankS = (int*)hS;
  int* rankK = (int*)hK;

  const int TB = 256;
  int gE    = (E + TB - 1) / TB;
  int gN32  = (N * 32 + TB - 1) / TB;
  int gN64  = (N * 64 + TB - 1) / TB;
  int gN8   = (N * 8 + TB - 1) / TB;
  int gNode4 = (N + 3) / 4;
  int nb    = (N + 1023) / 1024;

  // ---- CSR build (both graphs fused) ----
  hipLaunchKernelGGL(k_zero,  dim3((2 * N + TB - 1) / TB), dim3(TB), 0, stream, degS, 2 * N);
  hipLaunchKernelGGL(k_count_rank, dim3(gE), dim3(TB), 0, stream,
                     eiS, eiK, degS, degK, rankS, rankK, E);
  hipLaunchKernelGGL(k_scan1, dim3(nb, 2), dim3(TB), 0, stream, degS, degK, bsumS, bsumK, N);
  hipLaunchKernelGGL(k_scan2, dim3(2), dim3(128), 0, stream, bsumS, bsumK, nb, rsS, rsK, N);
  hipLaunchKernelGGL(k_scan3, dim3(nb, 2), dim3(TB), 0, stream,
                     degS, degK, bsumS, bsumK, rsS, rsK, N);
  hipLaunchKernelGGL(k_place, dim3(gE), dim3(TB), 0, stream,
                     eiS, eiK, rsS, rsK, rankS, rankK, colS, colK, E);

  // ---- layer 1 (input), both graphs fused via grid.y ----
  hipLaunchKernelGGL(k_gat_l1, dim3(gN8, 2), dim3(TB), 0, stream,
                     rsS, colS, rsK, colK, x,
                     W_in_src, b_in_src, a1_in_src, a2_in_src,
                     W_in_snk, b_in_snk, a1_in_snk, a2_in_snk,
                     seA, skA, N);

  // ---- layers 2..L ----
  for (int i = 0; i < L - 1; ++i){
    hipLaunchKernelGGL(k_linear, dim3(gN32), dim3(TB), 0, stream,
                       seA, skA, W_src + (size_t)i * 1024, W_snk + (size_t)i * 1024,
                       a1_src + i * 32, a2_src + i * 32, a1_snk + i * 32, a2_snk + i * 32,
                       hS, hK, a1Sv, a2Sv, a1Kv, a2Kv, N);
    hipLaunchKernelGGL(k_gat_agg, dim3(gNode4, 2), dim3(TB), 0, stream,
                       rsS, colS, hS, a1Sv, a2Sv, b_src + i * 32, seA,
                       rsK, colK, hK, a1Kv, a2Kv, b_snk + i * 32, skA, N);
  }

  // ---- heads ----
  hipLaunchKernelGGL(k_head0, dim3(gN64), dim3(TB), 0, stream,
                     seA, skA, W_o_src, b_o_src, W_o_snk, b_o_snk, comb, outp, N);
  hipLaunchKernelGGL(k_head1, dim3(gNode4), dim3(TB), 0, stream,
                     rsS, colS, rsK, colK, comb, x, W_d1, b_d1, outp, N);
}

// Round 7
// 846.539 us; speedup vs baseline: 2.1789x; 1.1053x over previous
//
#include <hip/hip_runtime.h>

#define NEG_SLOPE 0.2f
#define PRELU_W 0.1f

__device__ __forceinline__ float d_lrelu(float v){ return fmaxf(v, NEG_SLOPE * v); }
__device__ __forceinline__ float d_prelu(float v){ return fmaxf(v, PRELU_W * v); }

// bf16 helpers (round-to-nearest-even), no header dependency
__device__ __forceinline__ unsigned short f2bf(float f){
  unsigned int u = __builtin_bit_cast(unsigned int, f);
  unsigned int r = (u + 0x7fffu + ((u >> 16) & 1u)) >> 16;
  return (unsigned short)r;
}
__device__ __forceinline__ float bflo(unsigned int u){ return __builtin_bit_cast(float, u << 16); }
__device__ __forceinline__ float bfhi(unsigned int u){ return __builtin_bit_cast(float, u & 0xffff0000u); }

// ============================ CSR build ============================

__global__ void k_zero(int* __restrict__ p, int n){
  int i = blockIdx.x * 256 + threadIdx.x;
  if (i < n) p[i] = 0;
}

// Count degrees for BOTH graphs, 2 edges per thread (4 independent atomics in
// flight); atomicAdd's return IS the edge's rank within its destination.
__global__ void k_count_rank(const int* __restrict__ eiS, const int* __restrict__ eiK,
                             int* __restrict__ degS, int* __restrict__ degK,
                             int* __restrict__ rankS, int* __restrict__ rankK, int E){
  int e0 = blockIdx.x * 512 + threadIdx.x;
  int e1 = e0 + 256;
  bool v0 = e0 < E, v1 = e1 < E;
  int dS0 = 0, dK0 = 0, dS1 = 0, dK1 = 0;
  if (v0){ dS0 = eiS[E + e0]; dK0 = eiK[E + e0]; }
  if (v1){ dS1 = eiS[E + e1]; dK1 = eiK[E + e1]; }
  if (v0){
    rankS[e0] = atomicAdd(&degS[dS0], 1);
    rankK[e0] = atomicAdd(&degK[dK0], 1);
  }
  if (v1){
    rankS[e1] = atomicAdd(&degS[dS1], 1);
    rankK[e1] = atomicAdd(&degK[dK1], 1);
  }
}

// chunk=1024 per block (256 thr x 4); grid.y selects graph
__global__ void k_scan1(const int* __restrict__ degS, const int* __restrict__ degK,
                        int* __restrict__ bsumS, int* __restrict__ bsumK, int n){
  const int* deg = blockIdx.y ? degK : degS;
  int* bsum = blockIdx.y ? bsumK : bsumS;
  int b = blockIdx.x, t = threadIdx.x;
  int base = b * 1024 + t * 4;
  int s = 0;
  #pragma unroll
  for (int k2 = 0; k2 < 4; ++k2){ int i = base + k2; if (i < n) s += deg[i]; }
  #pragma unroll
  for (int d = 32; d >= 1; d >>= 1) s += __shfl_xor(s, d, 64);
  __shared__ int ws[4];
  int lane = t & 63, wid = t >> 6;
  if (lane == 0) ws[wid] = s;
  __syncthreads();
  if (t == 0) bsum[b] = ws[0] + ws[1] + ws[2] + ws[3];
}

// 2 blocks (one per graph), 128 threads: exclusive-scan bsum (nb <= 128)
__global__ void k_scan2(int* __restrict__ bsumS, int* __restrict__ bsumK, int nb,
                        int* __restrict__ rsS, int* __restrict__ rsK, int n){
  int* bsum = blockIdx.x ? bsumK : bsumS;
  int* rs = blockIdx.x ? rsK : rsS;
  int t = threadIdx.x;
  int v = (t < nb) ? bsum[t] : 0;
  int x = v;
  int lane = t & 63, wid = t >> 6;
  #pragma unroll
  for (int d = 1; d < 64; d <<= 1){ int y = __shfl_up(x, d, 64); if (lane >= d) x += y; }
  __shared__ int wq[2];
  if (lane == 63) wq[wid] = x;
  __syncthreads();
  if (wid == 1) x += wq[0];
  if (t < nb) bsum[t] = x - v;
  if (t == nb - 1) rs[n] = x;
}

__global__ void k_scan3(const int* __restrict__ degS, const int* __restrict__ degK,
                        const int* __restrict__ bsumS, const int* __restrict__ bsumK,
                        int* __restrict__ rsS, int* __restrict__ rsK, int n){
  const int* deg = blockIdx.y ? degK : degS;
  const int* bsum = blockIdx.y ? bsumK : bsumS;
  int* rs = blockIdx.y ? rsK : rsS;
  int b = blockIdx.x, t = threadIdx.x;
  int base = b * 1024 + t * 4;
  int v[4];
  #pragma unroll
  for (int k2 = 0; k2 < 4; ++k2){ int i = base + k2; v[k2] = (i < n) ? deg[i] : 0; }
  int tsum = v[0] + v[1] + v[2] + v[3];
  int x = tsum;
  int lane = t & 63, wid = t >> 6;
  #pragma unroll
  for (int d = 1; d < 64; d <<= 1){ int y = __shfl_up(x, d, 64); if (lane >= d) x += y; }
  __shared__ int ws[4];
  if (lane == 63) ws[wid] = x;
  __syncthreads();
  int woff = 0;
  for (int w = 0; w < wid; ++w) woff += ws[w];
  int run = bsum[b] + woff + (x - tsum);
  #pragma unroll
  for (int k2 = 0; k2 < 4; ++k2){ int i = base + k2; if (i < n) rs[i] = run; run += v[k2]; }
}

// Atomic-free placement: slot = rs[d] + precomputed rank. 2 edges/thread.
__global__ void k_place(const int* __restrict__ eiS, const int* __restrict__ eiK,
                        const int* __restrict__ rsS, const int* __restrict__ rsK,
                        const int* __restrict__ rankS, const int* __restrict__ rankK,
                        int* __restrict__ colS, int* __restrict__ colK, int E){
  int e0 = blockIdx.x * 512 + threadIdx.x;
  int e1 = e0 + 256;
  bool v0 = e0 < E, v1 = e1 < E;
  if (v0){
    int sS = eiS[e0], dS = eiS[E + e0];
    int sK = eiK[e0], dK = eiK[E + e0];
    int rS = rankS[e0], rK = rankK[e0];
    colS[rsS[dS] + rS] = sS;
    colK[rsK[dK] + rK] = sK;
  }
  if (v1){
    int sS = eiS[e1], dS = eiS[E + e1];
    int sK = eiK[e1], dK = eiK[E + e1];
    int rS = rankS[e1], rK = rankK[e1];
    colS[rsS[dS] + rS] = sS;
    colK[rsK[dK] + rK] = sK;
  }
}

// ============================ GAT layer 1 (x is [N,1]) ============================
// 8 lanes per node; p1/p2 computed once per block; float4 output writes.
__global__ void k_gat_l1(const int* __restrict__ rsA, const int* __restrict__ colA,
                         const int* __restrict__ rsB, const int* __restrict__ colB,
                         const float* __restrict__ x,
                         const float* __restrict__ WA, const float* __restrict__ bA,
                         const float* __restrict__ a1A, const float* __restrict__ a2A,
                         const float* __restrict__ WB, const float* __restrict__ bB,
                         const float* __restrict__ a1B, const float* __restrict__ a2B,
                         float* __restrict__ outA, float* __restrict__ outB, int n){
  bool g = (blockIdx.y != 0);
  const int* rs  = g ? rsB  : rsA;
  const int* col = g ? colB : colA;
  const float* W = g ? WB : WA;  const float* bias = g ? bB : bA;
  const float* a1 = g ? a1B : a1A; const float* a2 = g ? a2B : a2A;
  float* outp = g ? outB : outA;

  __shared__ float sp[2];
  int t = threadIdx.x;
  if (t < 32){
    float wk = W[t];
    float q1 = wk * a1[t], q2 = wk * a2[t];
    #pragma unroll
    for (int d = 16; d >= 1; d >>= 1){ q1 += __shfl_xor(q1, d, 32); q2 += __shfl_xor(q2, d, 32); }
    if (t == 0){ sp[0] = q1; sp[1] = q2; }
  }
  __syncthreads();
  float p1 = sp[0], p2 = sp[1];

  int gid = blockIdx.x * 256 + t;
  int node = gid >> 3, l8 = gid & 7;
  if (node >= n) return;
  float a2d = x[node] * p2;
  int beg = rs[node], end = rs[node + 1];
  float denom = 0.f, accx = 0.f;
  #pragma unroll 2
  for (int idx = beg + l8; idx < end; idx += 8){
    float xs = x[col[idx]];
    float w = __expf(d_lrelu(xs * p1 + a2d));
    denom += w;
    accx += w * xs;
  }
  #pragma unroll
  for (int d = 4; d >= 1; d >>= 1){
    denom += __shfl_xor(denom, d, 8);
    accx  += __shfl_xor(accx,  d, 8);
  }
  float r = accx / (denom + 1e-16f);
  float4 Wv = *(const float4*)(W + l8 * 4);
  float4 Bv = *(const float4*)(bias + l8 * 4);
  float4 o;
  o.x = d_prelu(r * Wv.x + Bv.x);
  o.y = d_prelu(r * Wv.y + Bv.y);
  o.z = d_prelu(r * Wv.z + Bv.z);
  o.w = d_prelu(r * Wv.w + Bv.w);
  *(float4*)(outp + (size_t)node * 32 + l8 * 4) = o;
}

// ============================ per-layer linear ============================
__global__ void k_linear(const float* __restrict__ se, const float* __restrict__ sk,
                         const float* __restrict__ WS, const float* __restrict__ WK,
                         const float* __restrict__ a1S, const float* __restrict__ a2S,
                         const float* __restrict__ a1K, const float* __restrict__ a2K,
                         unsigned short* __restrict__ hS, unsigned short* __restrict__ hK,
                         float* __restrict__ oa1S, float* __restrict__ oa2S,
                         float* __restrict__ oa1K, float* __restrict__ oa2K, int n){
  __shared__ float sWS[1024], sWK[1024], sa[128];
  int t = threadIdx.x;
  for (int i = t; i < 1024; i += 256){ sWS[i] = WS[i]; sWK[i] = WK[i]; }
  if (t < 32){ sa[t] = a1S[t]; sa[32 + t] = a2S[t]; sa[64 + t] = a1K[t]; sa[96 + t] = a2K[t]; }
  __syncthreads();
  int gid = blockIdx.x * 256 + t;
  int node = gid >> 5, k = gid & 31;
  if (node >= n) return;
  float c = se[node * 32 + k] + sk[node * 32 + k];
  float hs = 0.f, hk = 0.f;
  #pragma unroll
  for (int m = 0; m < 32; ++m){
    float cm = __shfl(c, m, 32);
    hs += cm * sWS[m * 32 + k];
    hk += cm * sWK[m * 32 + k];
  }
  hS[node * 32 + k] = f2bf(hs);
  hK[node * 32 + k] = f2bf(hk);
  float r1 = hs * sa[k], r2 = hs * sa[32 + k], r3 = hk * sa[64 + k], r4 = hk * sa[96 + k];
  #pragma unroll
  for (int d = 16; d >= 1; d >>= 1){
    r1 += __shfl_xor(r1, d, 32); r2 += __shfl_xor(r2, d, 32);
    r3 += __shfl_xor(r3, d, 32); r4 += __shfl_xor(r4, d, 32);
  }
  if (k == 0){ oa1S[node] = r1; oa2S[node] = r2; oa1K[node] = r3; oa2K[node] = r4; }
}

// ============================ generic GAT aggregation ============================
// 2 nodes per wave: per node 8 edge-groups x 4 k-lanes (uint4 = 8 bf16/lane).
// 16 concurrent edge streams per wave; reductions stay within 32-lane halves.
__global__ void k_gat_agg(const int* __restrict__ rsA, const int* __restrict__ colA,
                          const unsigned short* __restrict__ hA,
                          const float* __restrict__ a1A, const float* __restrict__ a2A,
                          const float* __restrict__ bA, float* __restrict__ outA,
                          const int* __restrict__ rsB, const int* __restrict__ colB,
                          const unsigned short* __restrict__ hB,
                          const float* __restrict__ a1B, const float* __restrict__ a2B,
                          const float* __restrict__ bB, float* __restrict__ outB, int n){
  bool g2 = (blockIdx.y != 0);
  const int* rs  = g2 ? rsB  : rsA;
  const int* col = g2 ? colB : colA;
  const unsigned short* h = g2 ? hB : hA;
  const float* a1 = g2 ? a1B : a1A;
  const float* a2 = g2 ? a2B : a2A;
  const float* bias = g2 ? bB : bA;
  float* outp = g2 ? outB : outA;

  int t = threadIdx.x;
  int lane = t & 63;
  int half = lane >> 5, l32 = lane & 31;
  int node = blockIdx.x * 8 + (t >> 6) * 2 + half;
  if (node >= n) return;
  int g = l32 >> 2;          // 8 edge groups
  int k = (l32 & 3) * 8;     // element offset: 8 bf16 per lane
  float a2d = a2[node];
  int beg = rs[node], end = rs[node + 1];
  float acc[8] = {0.f,0.f,0.f,0.f,0.f,0.f,0.f,0.f};
  float dpart = 0.f;
  #pragma unroll 2
  for (int idx = beg + g; idx < end; idx += 8){
    int s = col[idx];
    float w = __expf(d_lrelu(a1[s] + a2d));
    uint4 hv = *(const uint4*)(h + (((size_t)s) << 5) + k);
    dpart += w;
    acc[0] += w * bflo(hv.x); acc[1] += w * bfhi(hv.x);
    acc[2] += w * bflo(hv.y); acc[3] += w * bfhi(hv.y);
    acc[4] += w * bflo(hv.z); acc[5] += w * bfhi(hv.z);
    acc[6] += w * bflo(hv.w); acc[7] += w * bfhi(hv.w);
  }
  #pragma unroll
  for (int m = 4; m <= 16; m <<= 1){
    #pragma unroll
    for (int i = 0; i < 8; ++i) acc[i] += __shfl_xor(acc[i], m, 32);
    dpart += __shfl_xor(dpart, m, 32);
  }
  if (g == 0){
    float inv = 1.f / (dpart + 1e-16f);
    float4 b0 = *(const float4*)(bias + k);
    float4 b1 = *(const float4*)(bias + k + 4);
    float4 o0, o1;
    o0.x = d_prelu(acc[0] * inv + b0.x);
    o0.y = d_prelu(acc[1] * inv + b0.y);
    o0.z = d_prelu(acc[2] * inv + b0.z);
    o0.w = d_prelu(acc[3] * inv + b0.w);
    o1.x = d_prelu(acc[4] * inv + b1.x);
    o1.y = d_prelu(acc[5] * inv + b1.y);
    o1.z = d_prelu(acc[6] * inv + b1.z);
    o1.w = d_prelu(acc[7] * inv + b1.w);
    *(float4*)(outp + (size_t)node * 32 + k) = o0;
    *(float4*)(outp + (size_t)node * 32 + k + 4) = o1;
  }
}

// ============================ output head 0 ============================
__global__ void k_head0(const float* __restrict__ se, const float* __restrict__ sk,
                        const float* __restrict__ Wos, const float* __restrict__ bos,
                        const float* __restrict__ Wok, const float* __restrict__ bok,
                        unsigned short* __restrict__ comb, float* __restrict__ outp, int n){
  int gid = blockIdx.x * 256 + threadIdx.x;
  int node = gid >> 6, k = gid & 63;
  if (node >= n) return;
  float cv = (k < 32) ? se[node * 32 + k] : sk[node * 32 + (k - 32)];
  comb[(size_t)node * 64 + k] = f2bf(cv);
  float s0 = cv * Wos[k * 2], s1 = cv * Wos[k * 2 + 1];
  float q0 = cv * Wok[k * 2], q1 = cv * Wok[k * 2 + 1];
  #pragma unroll
  for (int d = 32; d >= 1; d >>= 1){
    s0 += __shfl_xor(s0, d, 64); s1 += __shfl_xor(s1, d, 64);
    q0 += __shfl_xor(q0, d, 64); q1 += __shfl_xor(q1, d, 64);
  }
  if (k == 0){
    float f0 = (fmaxf(s0 + bos[0], 0.f) + fmaxf(q0 + bok[0], 0.f)) * 0.5f;
    float f1 = (fmaxf(s1 + bos[1], 0.f) + fmaxf(q1 + bok[1], 0.f)) * 0.5f;
    outp[node * 4 + 0] = f0;
    outp[node * 4 + 1] = f1;
  }
}

// ============================ output head 1 (edge_neighbor) ============================
// One wave per node: 8 edge-groups x 8 k-lanes (uint4 = 8 bf16/lane, 128B row).
__global__ void k_head1(const int* __restrict__ rsS, const int* __restrict__ colS,
                        const int* __restrict__ rsK, const int* __restrict__ colK,
                        const unsigned short* __restrict__ comb, const float* __restrict__ x,
                        const float* __restrict__ Wd1, const float* __restrict__ bd1,
                        float* __restrict__ outp, int n){
  int lane = threadIdx.x & 63;
  int node = blockIdx.x * 4 + (threadIdx.x >> 6);
  if (node >= n) return;
  int g8 = lane >> 3, k8 = (lane & 7) * 8;
  float aS[8] = {0.f,0.f,0.f,0.f,0.f,0.f,0.f,0.f};
  float aK[8] = {0.f,0.f,0.f,0.f,0.f,0.f,0.f,0.f};
  {
    int beg = rsS[node], end = rsS[node + 1];
    #pragma unroll 2
    for (int idx = beg + g8; idx < end; idx += 8){
      int s = colS[idx];
      float xs = x[s];
      uint4 cv = *(const uint4*)(comb + (((size_t)s) << 6) + k8);
      aS[0] += xs * bflo(cv.x); aS[1] += xs * bfhi(cv.x);
      aS[2] += xs * bflo(cv.y); aS[3] += xs * bfhi(cv.y);
      aS[4] += xs * bflo(cv.z); aS[5] += xs * bfhi(cv.z);
      aS[6] += xs * bflo(cv.w); aS[7] += xs * bfhi(cv.w);
    }
  }
  {
    int beg = rsK[node], end = rsK[node + 1];
    #pragma unroll 2
    for (int idx = beg + g8; idx < end; idx += 8){
      int s = colK[idx];
      float xs = x[s];
      uint4 cv = *(const uint4*)(comb + (((size_t)s) << 6) + k8);
      aK[0] += xs * bflo(cv.x); aK[1] += xs * bfhi(cv.x);
      aK[2] += xs * bflo(cv.y); aK[3] += xs * bfhi(cv.y);
      aK[4] += xs * bflo(cv.z); aK[5] += xs * bfhi(cv.z);
      aK[6] += xs * bflo(cv.w); aK[7] += xs * bfhi(cv.w);
    }
  }
  #pragma unroll
  for (int m = 8; m <= 32; m <<= 1){
    #pragma unroll
    for (int i = 0; i < 8; ++i){
      aS[i] += __shfl_xor(aS[i], m, 64);
      aK[i] += __shfl_xor(aK[i], m, 64);
    }
  }
  // lanes 0..7 (g8==0) hold full sums for their k8 slice
  uint4 cs = *(const uint4*)(comb + (((size_t)node) << 6) + k8);
  float c[8] = { bflo(cs.x), bfhi(cs.x), bflo(cs.y), bfhi(cs.y),
                 bflo(cs.z), bfhi(cs.z), bflo(cs.w), bfhi(cs.w) };
  float r0 = 0.f, r1 = 0.f;
  #pragma unroll
  for (int i = 0; i < 8; ++i){
    float cd = c[i] * 0.5f;
    float tv = fmaxf(aS[i] + cd, 0.f) + fmaxf(aK[i] + cd, 0.f);
    float2 w = *(const float2*)(Wd1 + (k8 + i) * 2);
    r0 += tv * w.x;
    r1 += tv * w.y;
  }
  #pragma unroll
  for (int m = 1; m <= 4; m <<= 1){
    r0 += __shfl_xor(r0, m, 64);
    r1 += __shfl_xor(r1, m, 64);
  }
  if (lane == 0){
    outp[(size_t)node * 4 + 2] = fmaxf(r0 + bd1[0], 0.f);
    outp[(size_t)node * 4 + 3] = fmaxf(r1 + bd1[1], 0.f);
  }
}

// ============================ launch ============================

extern "C" void kernel_launch(void* const* d_in, const int* in_sizes, int n_in,
                              void* d_out, int out_size, void* d_ws, size_t ws_size,
                              hipStream_t stream) {
  const float* x      = (const float*)d_in[0];
  const int*   eiS    = (const int*)d_in[1];
  const int*   eiK    = (const int*)d_in[2];
  const float* W_in_src = (const float*)d_in[3];
  const float* b_in_src = (const float*)d_in[4];
  const float* a1_in_src= (const float*)d_in[5];
  const float* a2_in_src= (const float*)d_in[6];
  const float* W_in_snk = (const float*)d_in[7];
  const float* b_in_snk = (const float*)d_in[8];
  const float* a1_in_snk= (const float*)d_in[9];
  const float* a2_in_snk= (const float*)d_in[10];
  const float* W_src  = (const float*)d_in[11];
  const float* b_src  = (const float*)d_in[12];
  const float* a1_src = (const float*)d_in[13];
  const float* a2_src = (const float*)d_in[14];
  const float* W_snk  = (const float*)d_in[15];
  const float* b_snk  = (const float*)d_in[16];
  const float* a1_snk = (const float*)d_in[17];
  const float* a2_snk = (const float*)d_in[18];
  const float* W_o_src= (const float*)d_in[19];
  const float* b_o_src= (const float*)d_in[20];
  const float* W_o_snk= (const float*)d_in[21];
  const float* b_o_snk= (const float*)d_in[22];
  const float* W_d1   = (const float*)d_in[23];
  const float* b_d1   = (const float*)d_in[24];
  float* outp = (float*)d_out;

  const int N = in_sizes[0];       // 100000
  const int E = in_sizes[1] / 2;   // 1600000
  const int L = 5;

  // ---- workspace layout: floats, ints (16B-multiple total), then bf16 ----
  float* f = (float*)d_ws;
  float* seA = f;  f += (size_t)N * 32;
  float* skA = f;  f += (size_t)N * 32;
  float* a1Sv = f; f += N;
  float* a2Sv = f; f += N;
  float* a1Kv = f; f += N;
  float* a2Kv = f; f += N;
  int* ip = (int*)f;
  int* rsS    = ip; ip += N + 4;   // padded to keep 16B alignment downstream
  int* rsK    = ip; ip += N + 4;
  int* colS   = ip; ip += E;
  int* colK   = ip; ip += E;
  int* degS   = ip; ip += N;   // degS/degK adjacent -> single zero pass
  int* degK   = ip; ip += N;
  int* bsumS  = ip; ip += 256;
  int* bsumK  = ip; ip += 256;
  unsigned short* us = (unsigned short*)ip;
  unsigned short* hS   = us; us += (size_t)N * 32;
  unsigned short* hK   = us; us += (size_t)N * 32;
  unsigned short* comb = us; us += (size_t)N * 64;
  // rank arrays alias hS/hK: dead before k_linear first writes them
  int* rankS = (int*)hS;
  int* rankK = (int*)hK;

  const int TB = 256;
  int gE2   = (E + 511) / 512;
  int gN32  = (N * 32 + TB - 1) / TB;
  int gN64  = (N * 64 + TB - 1) / TB;
  int gN8   = (N * 8 + TB - 1) / TB;
  int gNode4 = (N + 3) / 4;
  int gNode8 = (N + 7) / 8;
  int nb    = (N + 1023) / 1024;

  // ---- CSR build (both graphs fused) ----
  hipLaunchKernelGGL(k_zero,  dim3((2 * N + TB - 1) / TB), dim3(TB), 0, stream, degS, 2 * N);
  hipLaunchKernelGGL(k_count_rank, dim3(gE2), dim3(TB), 0, stream,
                     eiS, eiK, degS, degK, rankS, rankK, E);
  hipLaunchKernelGGL(k_scan1, dim3(nb, 2), dim3(TB), 0, stream, degS, degK, bsumS, bsumK, N);
  hipLaunchKernelGGL(k_scan2, dim3(2), dim3(128), 0, stream, bsumS, bsumK, nb, rsS, rsK, N);
  hipLaunchKernelGGL(k_scan3, dim3(nb, 2), dim3(TB), 0, stream,
                     degS, degK, bsumS, bsumK, rsS, rsK, N);
  hipLaunchKernelGGL(k_place, dim3(gE2), dim3(TB), 0, stream,
                     eiS, eiK, rsS, rsK, rankS, rankK, colS, colK, E);

  // ---- layer 1 (input), both graphs fused via grid.y ----
  hipLaunchKernelGGL(k_gat_l1, dim3(gN8, 2), dim3(TB), 0, stream,
                     rsS, colS, rsK, colK, x,
                     W_in_src, b_in_src, a1_in_src, a2_in_src,
                     W_in_snk, b_in_snk, a1_in_snk, a2_in_snk,
                     seA, skA, N);

  // ---- layers 2..L ----
  for (int i = 0; i < L - 1; ++i){
    hipLaunchKernelGGL(k_linear, dim3(gN32), dim3(TB), 0, stream,
                       seA, skA, W_src + (size_t)i * 1024, W_snk + (size_t)i * 1024,
                       a1_src + i * 32, a2_src + i * 32, a1_snk + i * 32, a2_snk + i * 32,
                       hS, hK, a1Sv, a2Sv, a1Kv, a2Kv, N);
    hipLaunchKernelGGL(k_gat_agg, dim3(gNode8, 2), dim3(TB), 0, stream,
                       rsS, colS, hS, a1Sv, a2Sv, b_src + i * 32, seA,
                       rsK, colK, hK, a1Kv, a2Kv, b_snk + i * 32, skA, N);
  }

  // ---- heads ----
  hipLaunchKernelGGL(k_head0, dim3(gN64), dim3(TB), 0, stream,
                     seA, skA, W_o_src, b_o_src, W_o_snk, b_o_snk, comb, outp, N);
  hipLaunchKernelGGL(k_head1, dim3(gNode4), dim3(TB), 0, stream,
                     rsS, colS, rsK, colK, comb, x, W_d1, b_d1, outp, N);
}